// Round 1
// baseline (814.179 us; speedup 1.0000x reference)
//
#include <hip/hip_runtime.h>

#define NB 4
#define CIN 64
#define COUT 64
#define HH 128
#define WW 128
#define HW (HH*WW)
#define C_OFF 144
#define C_OM 216
#define KTOT 576   // CIN * 9

// d_ws layout:
//   om : NB*C_OM*HW floats   (offset channels 0..143, sigmoided mask 144..215)
//   wT : KTOT*COUT floats    (w_dcn transposed to [kk][o])

__global__ __launch_bounds__(256) void transpose_wdcn(const float* __restrict__ w,
                                                      float* __restrict__ wT) {
    int idx = blockIdx.x * 256 + threadIdx.x;
    if (idx < KTOT * COUT) {
        int o = idx & 63, kk = idx >> 6;
        wT[idx] = w[o * KTOT + kk];
    }
}

__global__ __launch_bounds__(256) void conv_om_kernel(
    const float* __restrict__ feature,
    const float* __restrict__ w_off, const float* __restrict__ b_off,
    const float* __restrict__ w_mask, const float* __restrict__ b_mask,
    float* __restrict__ om)
{
    int tid = threadIdx.x;
    int p = blockIdx.x * 256 + tid;      // pixel id over NB*HW
    int cg = blockIdx.y;                 // 0..53 -> co = 4*cg .. 4*cg+3 (no off/mask straddle: 144%4==0)
    int b  = p >> 14;
    int hw = p & (HW - 1);
    int ho = hw >> 7;
    int wo = hw & 127;
    int co0 = cg * 4;

    float acc[4];
    const float* wb[4];
#pragma unroll
    for (int j = 0; j < 4; ++j) {
        int co = co0 + j;
        if (co < C_OFF) { acc[j] = b_off[co];         wb[j] = w_off  + (size_t)co * KTOT; }
        else            { acc[j] = b_mask[co - C_OFF]; wb[j] = w_mask + (size_t)(co - C_OFF) * KTOT; }
    }

    const float* fb = feature + (size_t)b * CIN * HW;
    for (int ci = 0; ci < CIN; ++ci) {
        const float* fp = fb + ci * HW;
#pragma unroll
        for (int ky = 0; ky < 3; ++ky) {
            int y = ho + ky - 1;
            bool yv = (unsigned)y < (unsigned)HH;
#pragma unroll
            for (int kx = 0; kx < 3; ++kx) {
                int x = wo + kx - 1;
                float v = (yv && (unsigned)x < (unsigned)WW) ? fp[y * WW + x] : 0.f;
                int wi = ci * 9 + ky * 3 + kx;
#pragma unroll
                for (int j = 0; j < 4; ++j) acc[j] += v * wb[j][wi];
            }
        }
    }

    size_t obase = (size_t)b * C_OM * HW + hw;
#pragma unroll
    for (int j = 0; j < 4; ++j) {
        int co = co0 + j;
        float v = acc[j];
        if (co >= C_OFF) v = 1.f / (1.f + __expf(-v));   // sigmoid for mask channels
        om[obase + (size_t)co * HW] = v;
    }
}

__global__ __launch_bounds__(256) void dcn_kernel(
    const float* __restrict__ input,
    const float* __restrict__ om,
    const float* __restrict__ wT,
    const float* __restrict__ b_dcn,
    float* __restrict__ out)
{
    __shared__ float om_l[C_OM * 16];     // [ch][px]
    __shared__ float val_l[KTOT * 16];    // [kk][px], kk = c*9+k

    int tid  = threadIdx.x;
    int tile = blockIdx.x;                // 0..4095
    int b    = tile >> 10;                // 1024 tiles per batch
    int hw0  = (tile & 1023) << 4;        // 16-pixel tile, never crosses a row (128%16==0)
    int ho   = hw0 >> 7;
    int wo0  = hw0 & 127;

    const float* omg = om + (size_t)b * C_OM * HW + hw0;
    for (int i = tid; i < C_OM * 16; i += 256) {
        int ch = i >> 4, px = i & 15;
        om_l[i] = omg[(size_t)ch * HW + px];
    }
    __syncthreads();

    // ---- sampling: 16 px * 64 c pairs, 9 taps each ----
    for (int pair = tid; pair < 1024; pair += 256) {
        int px = pair & 15, c = pair >> 4;
        int dg = c >> 3;
        const float* plane = input + (size_t)(b * CIN + c) * HW;
        float yb = (float)(ho - 1);
        float xb = (float)(wo0 + px - 1);
#pragma unroll
        for (int k = 0; k < 9; ++k) {
            float dy = om_l[(dg * 18 + 2 * k) * 16 + px];
            float dx = om_l[(dg * 18 + 2 * k + 1) * 16 + px];
            float m  = om_l[(C_OFF + dg * 9 + k) * 16 + px];
            float ys = dy + yb + (float)(k / 3);
            float xs = dx + xb + (float)(k % 3);
            float y0f = floorf(ys), x0f = floorf(xs);
            float wy = ys - y0f, wx = xs - x0f;
            int y0 = (int)y0f, x0 = (int)x0f;
            bool yv0 = (unsigned)y0 < (unsigned)HH;
            bool yv1 = (unsigned)(y0 + 1) < (unsigned)HH;
            bool xv0 = (unsigned)x0 < (unsigned)WW;
            bool xv1 = (unsigned)(x0 + 1) < (unsigned)WW;
            const float* r0 = plane + y0 * WW + x0;
            float v00 = (yv0 && xv0) ? r0[0]      : 0.f;
            float v01 = (yv0 && xv1) ? r0[1]      : 0.f;
            float v10 = (yv1 && xv0) ? r0[WW]     : 0.f;
            float v11 = (yv1 && xv1) ? r0[WW + 1] : 0.f;
            float top = v00 + (v01 - v00) * wx;
            float bot = v10 + (v11 - v10) * wx;
            float v = top + (bot - top) * wy;
            val_l[(c * 9 + k) * 16 + px] = v * m;
        }
    }
    __syncthreads();

    // ---- dot: out[o, px] = b[o] + sum_kk wT[kk][o] * val[kk][px]; 2o x 2px per thread ----
    int o2 = tid & 31;
    int ph = tid >> 5;
    int o0 = o2 * 2, px0 = ph * 2;
    float a00 = b_dcn[o0],     a01 = b_dcn[o0];
    float a10 = b_dcn[o0 + 1], a11 = b_dcn[o0 + 1];
    for (int kk = 0; kk < KTOT; ++kk) {
        float2 wv = *reinterpret_cast<const float2*>(wT + kk * 64 + o0);
        float va = val_l[kk * 16 + px0];
        float vb = val_l[kk * 16 + px0 + 1];
        a00 += wv.x * va; a01 += wv.x * vb;
        a10 += wv.y * va; a11 += wv.y * vb;
    }
    float* ob = out + (size_t)b * COUT * HW + hw0;
    ob[(size_t)o0 * HW + px0]           = a00;
    ob[(size_t)o0 * HW + px0 + 1]       = a01;
    ob[(size_t)(o0 + 1) * HW + px0]     = a10;
    ob[(size_t)(o0 + 1) * HW + px0 + 1] = a11;
}

extern "C" void kernel_launch(void* const* d_in, const int* in_sizes, int n_in,
                              void* d_out, int out_size, void* d_ws, size_t ws_size,
                              hipStream_t stream) {
    const float* input   = (const float*)d_in[0];
    const float* feature = (const float*)d_in[1];
    const float* w_off   = (const float*)d_in[2];
    const float* b_off   = (const float*)d_in[3];
    const float* w_mask  = (const float*)d_in[4];
    const float* b_mask  = (const float*)d_in[5];
    const float* w_dcn   = (const float*)d_in[6];
    const float* b_dcn   = (const float*)d_in[7];
    float* out = (float*)d_out;

    float* om = (float*)d_ws;                          // NB*C_OM*HW floats (~56.6 MB)
    float* wT = om + (size_t)NB * C_OM * HW;           // KTOT*COUT floats

    transpose_wdcn<<<(KTOT * COUT + 255) / 256, 256, 0, stream>>>(w_dcn, wT);

    dim3 cgrid(NB * HW / 256, 54);
    conv_om_kernel<<<cgrid, 256, 0, stream>>>(feature, w_off, b_off, w_mask, b_mask, om);

    dcn_kernel<<<NB * HW / 16, 256, 0, stream>>>(input, om, wT, b_dcn, out);
}

// Round 2
// 529.607 us; speedup vs baseline: 1.5373x; 1.5373x over previous
//
#include <hip/hip_runtime.h>
#include <hip/hip_bf16.h>

#define NB 4
#define CIN 64
#define COUT 64
#define HH 128
#define WW 128
#define HW (HH*WW)
#define C_OFF 144
#define C_OM 216
#define C_PAD 224
#define KTOT 576   // CIN * 9

typedef __attribute__((ext_vector_type(8))) short bf16x8;
typedef __attribute__((ext_vector_type(4))) float f32x4;
typedef __attribute__((ext_vector_type(8))) unsigned short uv8;

__device__ inline unsigned short f2bf(float f) {
    union { float f; unsigned u; } v; v.f = f;
    unsigned r = (v.u + 0x7FFF + ((v.u >> 16) & 1)) >> 16;   // RNE
    return (unsigned short)r;
}

// ---------------- prep kernels ----------------

__global__ __launch_bounds__(256) void transpose_wdcn(const float* __restrict__ w,
                                                      float* __restrict__ wT) {
    int idx = blockIdx.x * 256 + threadIdx.x;
    if (idx < KTOT * COUT) {
        int o = idx & 63, kk = idx >> 6;
        wT[idx] = w[o * KTOT + kk];
    }
}

// feature [b][c][y][x] f32 -> fnhwc [b][y][x][c] bf16
__global__ __launch_bounds__(256) void to_nhwc_bf16(const float* __restrict__ f,
                                                    unsigned short* __restrict__ o) {
    int t = blockIdx.x * 256 + threadIdx.x;      // 65536 = NB*HW
    int b = t >> 14, yx = t & 16383;
    const float* src = f + (size_t)b * CIN * HW + yx;
    unsigned short* dst = o + (size_t)t * 64;
#pragma unroll
    for (int c8 = 0; c8 < 8; ++c8) {
        uv8 v;
#pragma unroll
        for (int j = 0; j < 8; ++j) v[j] = f2bf(src[(size_t)(c8 * 8 + j) * HW]);
        *(uv8*)(dst + c8 * 8) = v;
    }
}

// wB[co][t*64+ci] bf16, co in [0,224), zeros for co>=216
__global__ __launch_bounds__(256) void prep_wB(const float* __restrict__ w_off,
                                               const float* __restrict__ w_mask,
                                               unsigned short* __restrict__ wB) {
    int idx = blockIdx.x * 256 + threadIdx.x;    // 224*576
    if (idx >= C_PAD * KTOT) return;
    int co = idx / KTOT, k = idx - co * KTOT;
    int t = k >> 6, ci = k & 63;
    float v = 0.f;
    if (co < C_OFF)      v = w_off[(size_t)co * KTOT + ci * 9 + t];
    else if (co < C_OM)  v = w_mask[(size_t)(co - C_OFF) * KTOT + ci * 9 + t];
    wB[idx] = f2bf(v);
}

// ---------------- MFMA implicit-GEMM conv for offset+mask ----------------
// C[px 64][co 224] = im2col(feature)[px][K=576] * wB^T ; K order = tap*64+ci

__global__ __launch_bounds__(256, 4) void conv_om_mfma(
    const unsigned short* __restrict__ fnhwc,
    const unsigned short* __restrict__ wB,
    const float* __restrict__ b_off, const float* __restrict__ b_mask,
    float* __restrict__ om)
{
    __shared__ __align__(16) unsigned short Ash[64 * 64];   // [px][ci] bf16, XOR-swizzled 16B units

    int tid = threadIdx.x;
    int bid = blockIdx.x;                 // 1024 blocks
    int b   = bid >> 8;
    int hw0 = (bid & 255) << 6;           // 64-px tile, half a row
    int ho  = hw0 >> 7;
    int wo0 = hw0 & 127;
    int lane = tid & 63, wave = tid >> 6;
    int arow = lane & 15;                 // row/col within 16-tile
    int g    = lane >> 4;                 // k-group 0..3

    f32x4 acc[14];
#pragma unroll
    for (int n = 0; n < 14; ++n) acc[n] = (f32x4){0.f, 0.f, 0.f, 0.f};

    int px_w = tid >> 3;                  // staging: px 0..31 (+32 on rep 1)
    int c8_w = tid & 7;                   // 8-ci chunk

    for (int t = 0; t < 9; ++t) {
        int ky = t / 3, kx = t - ky * 3;
        int y = ho + ky - 1;
        bool yv = (unsigned)y < (unsigned)HH;
        __syncthreads();
#pragma unroll
        for (int rep = 0; rep < 2; ++rep) {
            int px = px_w + rep * 32;
            int x = wo0 + px + kx - 1;
            uv8 v = (uv8){0, 0, 0, 0, 0, 0, 0, 0};
            if (yv && (unsigned)x < (unsigned)WW)
                v = *(const uv8*)(fnhwc + ((size_t)((b * HH + y) * WW + x) << 6) + c8_w * 8);
            int off16 = (c8_w << 4) ^ ((px & 7) << 4);
            *(uv8*)((char*)Ash + px * 128 + off16) = v;
        }
        __syncthreads();
#pragma unroll
        for (int half = 0; half < 2; ++half) {
            int px = wave * 16 + arow;
            int kb = half * 64 + g * 16;  // byte offset of 8 bf16 along K
            bf16x8 a = *(const bf16x8*)((const char*)Ash + px * 128 + (kb ^ ((px & 7) << 4)));
            int kglob = t * 64 + half * 32 + g * 8;
#pragma unroll
            for (int n = 0; n < 14; ++n) {
                int co = n * 16 + arow;
                bf16x8 bf = *(const bf16x8*)(wB + (size_t)co * KTOT + kglob);
                acc[n] = __builtin_amdgcn_mfma_f32_16x16x32_bf16(a, bf, acc[n], 0, 0, 0);
            }
        }
    }

    // epilogue: D row=(lane>>4)*4+j (=px), col=lane&15 (=co)  [measured m89]
    int pxb = wave * 16 + g * 4;
    float* obase = om + (size_t)b * C_OM * HW + hw0 + pxb;
#pragma unroll
    for (int n = 0; n < 14; ++n) {
        int co = n * 16 + arow;
        if (co < C_OM) {
            float bias = (co < C_OFF) ? b_off[co] : b_mask[co - C_OFF];
            f32x4 r;
#pragma unroll
            for (int j = 0; j < 4; ++j) {
                float v = acc[n][j] + bias;
                if (co >= C_OFF) v = 1.f / (1.f + __expf(-v));
                r[j] = v;
            }
            *(f32x4*)(obase + (size_t)co * HW) = r;
        }
    }
}

// ---------------- fallback f32 conv (if ws too small) ----------------

__global__ __launch_bounds__(256) void conv_om_kernel(
    const float* __restrict__ feature,
    const float* __restrict__ w_off, const float* __restrict__ b_off,
    const float* __restrict__ w_mask, const float* __restrict__ b_mask,
    float* __restrict__ om)
{
    int tid = threadIdx.x;
    int p = blockIdx.x * 256 + tid;
    int cg = blockIdx.y;
    int b  = p >> 14;
    int hw = p & (HW - 1);
    int ho = hw >> 7;
    int wo = hw & 127;
    int co0 = cg * 4;

    float acc[4];
    const float* wb[4];
#pragma unroll
    for (int j = 0; j < 4; ++j) {
        int co = co0 + j;
        if (co < C_OFF) { acc[j] = b_off[co];          wb[j] = w_off  + (size_t)co * 576; }
        else            { acc[j] = b_mask[co - C_OFF]; wb[j] = w_mask + (size_t)(co - C_OFF) * 576; }
    }
    const float* fb = feature + (size_t)b * CIN * HW;
    for (int ci = 0; ci < CIN; ++ci) {
        const float* fp = fb + ci * HW;
#pragma unroll
        for (int ky = 0; ky < 3; ++ky) {
            int y = ho + ky - 1;
            bool yvb = (unsigned)y < (unsigned)HH;
#pragma unroll
            for (int kx = 0; kx < 3; ++kx) {
                int x = wo + kx - 1;
                float v = (yvb && (unsigned)x < (unsigned)WW) ? fp[y * WW + x] : 0.f;
                int wi = ci * 9 + ky * 3 + kx;
#pragma unroll
                for (int j = 0; j < 4; ++j) acc[j] += v * wb[j][wi];
            }
        }
    }
    size_t obase = (size_t)b * C_OM * HW + hw;
#pragma unroll
    for (int j = 0; j < 4; ++j) {
        int co = co0 + j;
        float v = acc[j];
        if (co >= C_OFF) v = 1.f / (1.f + __expf(-v));
        om[obase + (size_t)co * HW] = v;
    }
}

// ---------------- deformable sampling + output GEMM ----------------

__global__ __launch_bounds__(256) void dcn_kernel(
    const float* __restrict__ input,
    const float* __restrict__ om,
    const float* __restrict__ wT,
    const float* __restrict__ b_dcn,
    float* __restrict__ out)
{
    __shared__ float om_l[C_OM * 16];
    __shared__ float val_l[KTOT * 16];

    int tid  = threadIdx.x;
    int tile = blockIdx.x;
    int b    = tile >> 10;
    int hw0  = (tile & 1023) << 4;
    int ho   = hw0 >> 7;
    int wo0  = hw0 & 127;

    const float* omg = om + (size_t)b * C_OM * HW + hw0;
    for (int i = tid; i < C_OM * 16; i += 256) {
        int ch = i >> 4, px = i & 15;
        om_l[i] = omg[(size_t)ch * HW + px];
    }
    __syncthreads();

    for (int pair = tid; pair < 1024; pair += 256) {
        int px = pair & 15, c = pair >> 4;
        int dg = c >> 3;
        const float* plane = input + (size_t)(b * CIN + c) * HW;
        float yb = (float)(ho - 1);
        float xb = (float)(wo0 + px - 1);
#pragma unroll
        for (int k = 0; k < 9; ++k) {
            float dy = om_l[(dg * 18 + 2 * k) * 16 + px];
            float dx = om_l[(dg * 18 + 2 * k + 1) * 16 + px];
            float m  = om_l[(C_OFF + dg * 9 + k) * 16 + px];
            float ys = dy + yb + (float)(k / 3);
            float xs = dx + xb + (float)(k % 3);
            float y0f = floorf(ys), x0f = floorf(xs);
            float wy = ys - y0f, wx = xs - x0f;
            int y0 = (int)y0f, x0 = (int)x0f;
            bool yv0 = (unsigned)y0 < (unsigned)HH;
            bool yv1 = (unsigned)(y0 + 1) < (unsigned)HH;
            bool xv0 = (unsigned)x0 < (unsigned)WW;
            bool xv1 = (unsigned)(x0 + 1) < (unsigned)WW;
            const float* r0 = plane + y0 * WW + x0;
            float v00 = (yv0 && xv0) ? r0[0]      : 0.f;
            float v01 = (yv0 && xv1) ? r0[1]      : 0.f;
            float v10 = (yv1 && xv0) ? r0[WW]     : 0.f;
            float v11 = (yv1 && xv1) ? r0[WW + 1] : 0.f;
            float top = v00 + (v01 - v00) * wx;
            float bot = v10 + (v11 - v10) * wx;
            float v = top + (bot - top) * wy;
            val_l[(c * 9 + k) * 16 + px] = v * m;
        }
    }
    __syncthreads();

    int o2 = tid & 31;
    int ph = tid >> 5;
    int o0 = o2 * 2, px0 = ph * 2;
    float a00 = b_dcn[o0],     a01 = b_dcn[o0];
    float a10 = b_dcn[o0 + 1], a11 = b_dcn[o0 + 1];
    for (int kk = 0; kk < KTOT; ++kk) {
        float2 wv = *reinterpret_cast<const float2*>(wT + kk * 64 + o0);
        float va = val_l[kk * 16 + px0];
        float vb = val_l[kk * 16 + px0 + 1];
        a00 += wv.x * va; a01 += wv.x * vb;
        a10 += wv.y * va; a11 += wv.y * vb;
    }
    float* ob = out + (size_t)b * COUT * HW + hw0;
    ob[(size_t)o0 * HW + px0]           = a00;
    ob[(size_t)o0 * HW + px0 + 1]       = a01;
    ob[(size_t)(o0 + 1) * HW + px0]     = a10;
    ob[(size_t)(o0 + 1) * HW + px0 + 1] = a11;
}

extern "C" void kernel_launch(void* const* d_in, const int* in_sizes, int n_in,
                              void* d_out, int out_size, void* d_ws, size_t ws_size,
                              hipStream_t stream) {
    const float* input   = (const float*)d_in[0];
    const float* feature = (const float*)d_in[1];
    const float* w_off   = (const float*)d_in[2];
    const float* b_off   = (const float*)d_in[3];
    const float* w_mask  = (const float*)d_in[4];
    const float* b_mask  = (const float*)d_in[5];
    const float* w_dcn   = (const float*)d_in[6];
    const float* b_dcn   = (const float*)d_in[7];
    float* out = (float*)d_out;

    // ws layout
    float* om = (float*)d_ws;                                   // 56.62 MB
    float* wT = om + (size_t)NB * C_OM * HW;                    // 147 KB
    unsigned short* fnhwc = (unsigned short*)(wT + KTOT * COUT); // 8.39 MB
    unsigned short* wBp   = fnhwc + (size_t)NB * HW * CIN;       // 258 KB
    size_t need = (size_t)((char*)(wBp + C_PAD * KTOT) - (char*)d_ws);

    transpose_wdcn<<<(KTOT * COUT + 255) / 256, 256, 0, stream>>>(w_dcn, wT);

    if (ws_size >= need) {
        to_nhwc_bf16<<<NB * HW / 256, 256, 0, stream>>>(feature, fnhwc);
        prep_wB<<<(C_PAD * KTOT + 255) / 256, 256, 0, stream>>>(w_off, w_mask, wBp);
        conv_om_mfma<<<NB * HW / 64, 256, 0, stream>>>(fnhwc, wBp, b_off, b_mask, om);
    } else {
        dim3 cgrid(NB * HW / 256, 54);
        conv_om_kernel<<<cgrid, 256, 0, stream>>>(feature, w_off, b_off, w_mask, b_mask, om);
    }

    dcn_kernel<<<NB * HW / 16, 256, 0, stream>>>(input, om, wT, b_dcn, out);
}

// Round 5
// 283.508 us; speedup vs baseline: 2.8718x; 1.8681x over previous
//
#include <hip/hip_runtime.h>
#include <hip/hip_bf16.h>

#define NB 4
#define CIN 64
#define COUT 64
#define HH 128
#define WW 128
#define HW (HH*WW)
#define C_OFF 144
#define C_OM 216
#define C_PAD 224
#define KTOT 576   // CIN * 9

typedef __attribute__((ext_vector_type(8))) short bf16x8;
typedef __attribute__((ext_vector_type(4))) float f32x4;
typedef __attribute__((ext_vector_type(8))) unsigned short uv8;

__device__ inline unsigned short f2bf(float f) {
    union { float f; unsigned u; } v; v.f = f;
    unsigned r = (v.u + 0x7FFF + ((v.u >> 16) & 1)) >> 16;   // RNE
    return (unsigned short)r;
}

// ---------------- prep kernels ----------------

__global__ __launch_bounds__(256) void transpose_wdcn(const float* __restrict__ w,
                                                      float* __restrict__ wT) {
    int idx = blockIdx.x * 256 + threadIdx.x;
    if (idx < KTOT * COUT) {
        int o = idx & 63, kk = idx >> 6;
        wT[idx] = w[o * KTOT + kk];
    }
}

// feature [b][c][y][x] f32 -> bf16 NHWC
__global__ __launch_bounds__(256) void to_nhwc_bf16(const float* __restrict__ f,
                                                    unsigned short* __restrict__ o) {
    int t = blockIdx.x * 256 + threadIdx.x;      // 65536 = NB*HW
    int b = t >> 14, yx = t & 16383;
    const float* src = f + (size_t)b * CIN * HW + yx;
    unsigned short* dst = o + (size_t)t * 64;
#pragma unroll
    for (int c8 = 0; c8 < 8; ++c8) {
        uv8 v;
#pragma unroll
        for (int j = 0; j < 8; ++j) v[j] = f2bf(src[(size_t)(c8 * 8 + j) * HW]);
        *(uv8*)(dst + c8 * 8) = v;
    }
}

// wB[co][t*64+ci] bf16, co in [0,224), zeros for co>=216
__global__ __launch_bounds__(256) void prep_wB(const float* __restrict__ w_off,
                                               const float* __restrict__ w_mask,
                                               unsigned short* __restrict__ wB) {
    int idx = blockIdx.x * 256 + threadIdx.x;    // 224*576
    if (idx >= C_PAD * KTOT) return;
    int co = idx / KTOT, k = idx - co * KTOT;
    int t = k >> 6, ci = k & 63;
    float v = 0.f;
    if (co < C_OFF)      v = w_off[(size_t)co * KTOT + ci * 9 + t];
    else if (co < C_OM)  v = w_mask[(size_t)(co - C_OFF) * KTOT + ci * 9 + t];
    wB[idx] = f2bf(v);
}

// wTf[q][co][r] bf16 = w_dcn[co][q*8+r]   (q in [0,72), r in [0,8); kk = q*8+r = ci*9+tap)
__global__ __launch_bounds__(256) void prep_wTf(const float* __restrict__ w,
                                                unsigned short* __restrict__ wTf) {
    int idx = blockIdx.x * 256 + threadIdx.x;    // 72*64*8 = 36864
    if (idx >= 72 * 64 * 8) return;
    int q = idx >> 9;
    int co = (idx >> 3) & 63;
    int r = idx & 7;
    wTf[idx] = f2bf(w[(size_t)co * KTOT + q * 8 + r]);
}

// ---------------- MFMA implicit-GEMM conv for offset+mask (validated R2) ----------------

__global__ __launch_bounds__(256, 4) void conv_om_mfma(
    const unsigned short* __restrict__ fnhwc,
    const unsigned short* __restrict__ wB,
    const float* __restrict__ b_off, const float* __restrict__ b_mask,
    float* __restrict__ om)
{
    __shared__ __align__(16) unsigned short Ash[64 * 64];

    int tid = threadIdx.x;
    int bid = blockIdx.x;
    int b   = bid >> 8;
    int hw0 = (bid & 255) << 6;
    int ho  = hw0 >> 7;
    int wo0 = hw0 & 127;
    int lane = tid & 63, wave = tid >> 6;
    int arow = lane & 15;
    int g    = lane >> 4;

    f32x4 acc[14];
#pragma unroll
    for (int n = 0; n < 14; ++n) acc[n] = (f32x4){0.f, 0.f, 0.f, 0.f};

    int px_w = tid >> 3;
    int c8_w = tid & 7;

    for (int t = 0; t < 9; ++t) {
        int ky = t / 3, kx = t - ky * 3;
        int y = ho + ky - 1;
        bool yv = (unsigned)y < (unsigned)HH;
        __syncthreads();
#pragma unroll
        for (int rep = 0; rep < 2; ++rep) {
            int px = px_w + rep * 32;
            int x = wo0 + px + kx - 1;
            uv8 v = (uv8){0, 0, 0, 0, 0, 0, 0, 0};
            if (yv && (unsigned)x < (unsigned)WW)
                v = *(const uv8*)(fnhwc + ((size_t)((b * HH + y) * WW + x) << 6) + c8_w * 8);
            int off16 = (c8_w << 4) ^ ((px & 7) << 4);
            *(uv8*)((char*)Ash + px * 128 + off16) = v;
        }
        __syncthreads();
#pragma unroll
        for (int half = 0; half < 2; ++half) {
            int px = wave * 16 + arow;
            int kb = half * 64 + g * 16;
            bf16x8 a = *(const bf16x8*)((const char*)Ash + px * 128 + (kb ^ ((px & 7) << 4)));
            int kglob = t * 64 + half * 32 + g * 8;
#pragma unroll
            for (int n = 0; n < 14; ++n) {
                int co = n * 16 + arow;
                bf16x8 bf = *(const bf16x8*)(wB + (size_t)co * KTOT + kglob);
                acc[n] = __builtin_amdgcn_mfma_f32_16x16x32_bf16(a, bf, acc[n], 0, 0, 0);
            }
        }
    }

    int pxb = wave * 16 + g * 4;
    float* obase = om + (size_t)b * C_OM * HW + hw0 + pxb;
#pragma unroll
    for (int n = 0; n < 14; ++n) {
        int co = n * 16 + arow;
        if (co < C_OM) {
            float bias = (co < C_OFF) ? b_off[co] : b_mask[co - C_OFF];
            f32x4 r;
#pragma unroll
            for (int j = 0; j < 4; ++j) {
                float v = acc[n][j] + bias;
                if (co >= C_OFF) v = 1.f / (1.f + __expf(-v));
                r[j] = v;
            }
            *(f32x4*)(obase + (size_t)co * HW) = r;
        }
    }
}

// ---------------- DCN: validated R2 sampling + MFMA dot graft ----------------
// Identical to the R2-PASSing dcn_kernel except: val stored as bf16 in
// k-octet layout val_q[q=kk/8][px][r=kk%8], and the 576-iter scalar dot
// replaced by 18 MFMA steps per wave against wTf.

__global__ __launch_bounds__(256) void dcn_kernel2(
    const float* __restrict__ input,          // NCHW f32 (original)
    const float* __restrict__ om,
    const unsigned short* __restrict__ wTf,   // [72][64][8] bf16
    const float* __restrict__ b_dcn,
    float* __restrict__ out)
{
    __shared__ float om_l[C_OM * 16];                       // 13824 B
    __shared__ __align__(16) unsigned short val_q[72 * 16 * 8];  // 18432 B

    int tid  = threadIdx.x;
    int tile = blockIdx.x;
    int b    = tile >> 10;
    int hw0  = (tile & 1023) << 4;
    int ho   = hw0 >> 7;
    int wo0  = hw0 & 127;

    const float* omg = om + (size_t)b * C_OM * HW + hw0;
    for (int i = tid; i < C_OM * 16; i += 256) {
        int ch = i >> 4, px = i & 15;
        om_l[i] = omg[(size_t)ch * HW + px];
    }
    __syncthreads();

    // ---- sampling: verbatim R2 logic, output quantized to bf16 in val_q ----
    for (int pair = tid; pair < 1024; pair += 256) {
        int px = pair & 15, c = pair >> 4;
        int dg = c >> 3;
        const float* plane = input + (size_t)(b * CIN + c) * HW;
        float yb = (float)(ho - 1);
        float xb = (float)(wo0 + px - 1);
#pragma unroll
        for (int k = 0; k < 9; ++k) {
            float dyv = om_l[(dg * 18 + 2 * k) * 16 + px];
            float dxv = om_l[(dg * 18 + 2 * k + 1) * 16 + px];
            float m  = om_l[(C_OFF + dg * 9 + k) * 16 + px];
            float ys = dyv + yb + (float)(k / 3);
            float xs = dxv + xb + (float)(k % 3);
            float y0f = floorf(ys), x0f = floorf(xs);
            float wy = ys - y0f, wx = xs - x0f;
            int y0 = (int)y0f, x0 = (int)x0f;
            bool yv0 = (unsigned)y0 < (unsigned)HH;
            bool yv1 = (unsigned)(y0 + 1) < (unsigned)HH;
            bool xv0 = (unsigned)x0 < (unsigned)WW;
            bool xv1 = (unsigned)(x0 + 1) < (unsigned)WW;
            const float* r0 = plane + y0 * WW + x0;
            float v00 = (yv0 && xv0) ? r0[0]      : 0.f;
            float v01 = (yv0 && xv1) ? r0[1]      : 0.f;
            float v10 = (yv1 && xv0) ? r0[WW]     : 0.f;
            float v11 = (yv1 && xv1) ? r0[WW + 1] : 0.f;
            float top = v00 + (v01 - v00) * wx;
            float bot = v10 + (v11 - v10) * wx;
            float v = top + (bot - top) * wy;
            int kk = c * 9 + k;
            val_q[(kk >> 3) * 128 + px * 8 + (kk & 7)] = f2bf(v * m);
        }
    }
    __syncthreads();

    // ---- MFMA dot: wave w -> co tile [w*16, w*16+16), 18 K-steps of 32 ----
    int lane = tid & 63, wave = tid >> 6;
    int arow = lane & 15, g = lane >> 4;
    int co = wave * 16 + arow;

    f32x4 acc = (f32x4){0.f, 0.f, 0.f, 0.f};
#pragma unroll
    for (int s = 0; s < 18; ++s) {
        int q = s * 4 + g;                // k-octet index; k = q*8 + j
        bf16x8 a  = *(const bf16x8*)(val_q + q * 128 + arow * 8);
        bf16x8 bf = *(const bf16x8*)(wTf + ((size_t)q * 64 + co) * 8);
        acc = __builtin_amdgcn_mfma_f32_16x16x32_bf16(a, bf, acc, 0, 0, 0);
    }

    // D: row=(lane>>4)*4+j -> px, col=arow -> co (conv-validated mapping)
    float bias = b_dcn[co];
    float* ob = out + (size_t)b * COUT * HW + (size_t)co * HW + hw0 + g * 4;
    f32x4 r;
#pragma unroll
    for (int j = 0; j < 4; ++j) r[j] = acc[j] + bias;
    *(f32x4*)ob = r;
}

// ---------------- fallback f32 kernels (if ws too small) ----------------

__global__ __launch_bounds__(256) void conv_om_kernel(
    const float* __restrict__ feature,
    const float* __restrict__ w_off, const float* __restrict__ b_off,
    const float* __restrict__ w_mask, const float* __restrict__ b_mask,
    float* __restrict__ om)
{
    int tid = threadIdx.x;
    int p = blockIdx.x * 256 + tid;
    int cg = blockIdx.y;
    int b  = p >> 14;
    int hw = p & (HW - 1);
    int ho = hw >> 7;
    int wo = hw & 127;
    int co0 = cg * 4;

    float acc[4];
    const float* wb[4];
#pragma unroll
    for (int j = 0; j < 4; ++j) {
        int co = co0 + j;
        if (co < C_OFF) { acc[j] = b_off[co];          wb[j] = w_off  + (size_t)co * 576; }
        else            { acc[j] = b_mask[co - C_OFF]; wb[j] = w_mask + (size_t)(co - C_OFF) * 576; }
    }
    const float* fb = feature + (size_t)b * CIN * HW;
    for (int ci = 0; ci < CIN; ++ci) {
        const float* fp = fb + ci * HW;
#pragma unroll
        for (int ky = 0; ky < 3; ++ky) {
            int y = ho + ky - 1;
            bool yvb = (unsigned)y < (unsigned)HH;
#pragma unroll
            for (int kx = 0; kx < 3; ++kx) {
                int x = wo + kx - 1;
                float v = (yvb && (unsigned)x < (unsigned)WW) ? fp[y * WW + x] : 0.f;
                int wi = ci * 9 + ky * 3 + kx;
#pragma unroll
                for (int j = 0; j < 4; ++j) acc[j] += v * wb[j][wi];
            }
        }
    }
    size_t obase = (size_t)b * C_OM * HW + hw;
#pragma unroll
    for (int j = 0; j < 4; ++j) {
        int co = co0 + j;
        float v = acc[j];
        if (co >= C_OFF) v = 1.f / (1.f + __expf(-v));
        om[obase + (size_t)co * HW] = v;
    }
}

__global__ __launch_bounds__(256) void dcn_kernel(
    const float* __restrict__ input,
    const float* __restrict__ om,
    const float* __restrict__ wT,
    const float* __restrict__ b_dcn,
    float* __restrict__ out)
{
    __shared__ float om_l[C_OM * 16];
    __shared__ float val_l[KTOT * 16];

    int tid  = threadIdx.x;
    int tile = blockIdx.x;
    int b    = tile >> 10;
    int hw0  = (tile & 1023) << 4;
    int ho   = hw0 >> 7;
    int wo0  = hw0 & 127;

    const float* omg = om + (size_t)b * C_OM * HW + hw0;
    for (int i = tid; i < C_OM * 16; i += 256) {
        int ch = i >> 4, px = i & 15;
        om_l[i] = omg[(size_t)ch * HW + px];
    }
    __syncthreads();

    for (int pair = tid; pair < 1024; pair += 256) {
        int px = pair & 15, c = pair >> 4;
        int dg = c >> 3;
        const float* plane = input + (size_t)(b * CIN + c) * HW;
        float yb = (float)(ho - 1);
        float xb = (float)(wo0 + px - 1);
#pragma unroll
        for (int k = 0; k < 9; ++k) {
            float dyv = om_l[(dg * 18 + 2 * k) * 16 + px];
            float dxv = om_l[(dg * 18 + 2 * k + 1) * 16 + px];
            float m  = om_l[(C_OFF + dg * 9 + k) * 16 + px];
            float ys = dyv + yb + (float)(k / 3);
            float xs = dxv + xb + (float)(k % 3);
            float y0f = floorf(ys), x0f = floorf(xs);
            float wy = ys - y0f, wx = xs - x0f;
            int y0 = (int)y0f, x0 = (int)x0f;
            bool yv0 = (unsigned)y0 < (unsigned)HH;
            bool yv1 = (unsigned)(y0 + 1) < (unsigned)HH;
            bool xv0 = (unsigned)x0 < (unsigned)WW;
            bool xv1 = (unsigned)(x0 + 1) < (unsigned)WW;
            const float* r0 = plane + y0 * WW + x0;
            float v00 = (yv0 && xv0) ? r0[0]      : 0.f;
            float v01 = (yv0 && xv1) ? r0[1]      : 0.f;
            float v10 = (yv1 && xv0) ? r0[WW]     : 0.f;
            float v11 = (yv1 && xv1) ? r0[WW + 1] : 0.f;
            float top = v00 + (v01 - v00) * wx;
            float bot = v10 + (v11 - v10) * wx;
            float v = top + (bot - top) * wy;
            val_l[(c * 9 + k) * 16 + px] = v * m;
        }
    }
    __syncthreads();

    int o2 = tid & 31;
    int ph = tid >> 5;
    int o0 = o2 * 2, px0 = ph * 2;
    float a00 = b_dcn[o0],     a01 = b_dcn[o0];
    float a10 = b_dcn[o0 + 1], a11 = b_dcn[o0 + 1];
    for (int kk = 0; kk < KTOT; ++kk) {
        float2 wv = *reinterpret_cast<const float2*>(wT + kk * 64 + o0);
        float va = val_l[kk * 16 + px0];
        float vb = val_l[kk * 16 + px0 + 1];
        a00 += wv.x * va; a01 += wv.x * vb;
        a10 += wv.y * va; a11 += wv.y * vb;
    }
    float* ob = out + (size_t)b * COUT * HW + hw0;
    ob[(size_t)o0 * HW + px0]           = a00;
    ob[(size_t)o0 * HW + px0 + 1]       = a01;
    ob[(size_t)(o0 + 1) * HW + px0]     = a10;
    ob[(size_t)(o0 + 1) * HW + px0 + 1] = a11;
}

extern "C" void kernel_launch(void* const* d_in, const int* in_sizes, int n_in,
                              void* d_out, int out_size, void* d_ws, size_t ws_size,
                              hipStream_t stream) {
    const float* input   = (const float*)d_in[0];
    const float* feature = (const float*)d_in[1];
    const float* w_off   = (const float*)d_in[2];
    const float* b_off   = (const float*)d_in[3];
    const float* w_mask  = (const float*)d_in[4];
    const float* b_mask  = (const float*)d_in[5];
    const float* w_dcn   = (const float*)d_in[6];
    const float* b_dcn   = (const float*)d_in[7];
    float* out = (float*)d_out;

    // ws layout (full path):
    float* om = (float*)d_ws;                                        // 56.62 MB
    unsigned short* fnhwc = (unsigned short*)(om + (size_t)NB * C_OM * HW); // 8.39 MB
    unsigned short* wBp   = fnhwc + (size_t)NB * HW * CIN;           // 258 KB
    unsigned short* wTfp  = wBp + (size_t)C_PAD * KTOT;              // 73.7 KB
    size_t need = (size_t)((char*)(wTfp + 72 * 64 * 8) - (char*)d_ws);

    if (ws_size >= need) {
        to_nhwc_bf16<<<NB * HW / 256, 256, 0, stream>>>(feature, fnhwc);
        prep_wB<<<(C_PAD * KTOT + 255) / 256, 256, 0, stream>>>(w_off, w_mask, wBp);
        prep_wTf<<<(72 * 64 * 8 + 255) / 256, 256, 0, stream>>>(w_dcn, wTfp);
        conv_om_mfma<<<NB * HW / 64, 256, 0, stream>>>(fnhwc, wBp, b_off, b_mask, om);
        dcn_kernel2<<<NB * HW / 16, 256, 0, stream>>>(input, om, wTfp, b_dcn, out);
    } else {
        // fallback: pure f32 path (R1-validated)
        float* wT = om + (size_t)NB * C_OM * HW;
        transpose_wdcn<<<(KTOT * COUT + 255) / 256, 256, 0, stream>>>(w_dcn, wT);
        dim3 cgrid(NB * HW / 256, 54);
        conv_om_kernel<<<cgrid, 256, 0, stream>>>(feature, w_off, b_off, w_mask, b_mask, om);
        dcn_kernel<<<NB * HW / 16, 256, 0, stream>>>(input, om, wT, b_dcn, out);
    }
}

// Round 6
// 270.776 us; speedup vs baseline: 3.0068x; 1.0470x over previous
//
#include <hip/hip_runtime.h>
#include <hip/hip_bf16.h>

#define NB 4
#define CIN 64
#define COUT 64
#define HH 128
#define WW 128
#define HW (HH*WW)
#define C_OFF 144
#define C_OM 216
#define C_PAD 224
#define KTOT 576   // CIN * 9

typedef __attribute__((ext_vector_type(8))) short bf16x8;
typedef __attribute__((ext_vector_type(4))) float f32x4;
typedef __attribute__((ext_vector_type(8))) unsigned short uv8;

__device__ inline unsigned short f2bf(float f) {
    union { float f; unsigned u; } v; v.f = f;
    unsigned r = (v.u + 0x7FFF + ((v.u >> 16) & 1)) >> 16;   // RNE
    return (unsigned short)r;
}

// ---------------- prep kernels ----------------

__global__ __launch_bounds__(256) void transpose_wdcn(const float* __restrict__ w,
                                                      float* __restrict__ wT) {
    int idx = blockIdx.x * 256 + threadIdx.x;
    if (idx < KTOT * COUT) {
        int o = idx & 63, kk = idx >> 6;
        wT[idx] = w[o * KTOT + kk];
    }
}

// feature [b][c][y][x] f32 -> bf16 NHWC
__global__ __launch_bounds__(256) void to_nhwc_bf16(const float* __restrict__ f,
                                                    unsigned short* __restrict__ o) {
    int t = blockIdx.x * 256 + threadIdx.x;      // 65536 = NB*HW
    int b = t >> 14, yx = t & 16383;
    const float* src = f + (size_t)b * CIN * HW + yx;
    unsigned short* dst = o + (size_t)t * 64;
#pragma unroll
    for (int c8 = 0; c8 < 8; ++c8) {
        uv8 v;
#pragma unroll
        for (int j = 0; j < 8; ++j) v[j] = f2bf(src[(size_t)(c8 * 8 + j) * HW]);
        *(uv8*)(dst + c8 * 8) = v;
    }
}

// wB[co][t*64+ci] bf16, co in [0,224), zeros for co>=216
__global__ __launch_bounds__(256) void prep_wB(const float* __restrict__ w_off,
                                               const float* __restrict__ w_mask,
                                               unsigned short* __restrict__ wB) {
    int idx = blockIdx.x * 256 + threadIdx.x;    // 224*576
    if (idx >= C_PAD * KTOT) return;
    int co = idx / KTOT, k = idx - co * KTOT;
    int t = k >> 6, ci = k & 63;
    float v = 0.f;
    if (co < C_OFF)      v = w_off[(size_t)co * KTOT + ci * 9 + t];
    else if (co < C_OM)  v = w_mask[(size_t)(co - C_OFF) * KTOT + ci * 9 + t];
    wB[idx] = f2bf(v);
}

// wTf2[q][co][r] bf16 = w_dcn[co][(dg*8+r)*9 + k], q = k*8+dg  (kk2 = tap*64+c order)
__global__ __launch_bounds__(256) void prep_wTf2(const float* __restrict__ w,
                                                 unsigned short* __restrict__ wTf2) {
    int idx = blockIdx.x * 256 + threadIdx.x;    // 72*64*8 = 36864
    if (idx >= 72 * 64 * 8) return;
    int q = idx >> 9;
    int co = (idx >> 3) & 63;
    int r = idx & 7;
    int k = q >> 3, dg = q & 7;
    wTf2[idx] = f2bf(w[(size_t)co * KTOT + (dg * 8 + r) * 9 + k]);
}

// ---------------- MFMA implicit-GEMM conv for offset+mask (validated R2) ----------------

__global__ __launch_bounds__(256, 4) void conv_om_mfma(
    const unsigned short* __restrict__ fnhwc,
    const unsigned short* __restrict__ wB,
    const float* __restrict__ b_off, const float* __restrict__ b_mask,
    float* __restrict__ om)
{
    __shared__ __align__(16) unsigned short Ash[64 * 64];

    int tid = threadIdx.x;
    int bid = blockIdx.x;
    int b   = bid >> 8;
    int hw0 = (bid & 255) << 6;
    int ho  = hw0 >> 7;
    int wo0 = hw0 & 127;
    int lane = tid & 63, wave = tid >> 6;
    int arow = lane & 15;
    int g    = lane >> 4;

    f32x4 acc[14];
#pragma unroll
    for (int n = 0; n < 14; ++n) acc[n] = (f32x4){0.f, 0.f, 0.f, 0.f};

    int px_w = tid >> 3;
    int c8_w = tid & 7;

    for (int t = 0; t < 9; ++t) {
        int ky = t / 3, kx = t - ky * 3;
        int y = ho + ky - 1;
        bool yv = (unsigned)y < (unsigned)HH;
        __syncthreads();
#pragma unroll
        for (int rep = 0; rep < 2; ++rep) {
            int px = px_w + rep * 32;
            int x = wo0 + px + kx - 1;
            uv8 v = (uv8){0, 0, 0, 0, 0, 0, 0, 0};
            if (yv && (unsigned)x < (unsigned)WW)
                v = *(const uv8*)(fnhwc + ((size_t)((b * HH + y) * WW + x) << 6) + c8_w * 8);
            int off16 = (c8_w << 4) ^ ((px & 7) << 4);
            *(uv8*)((char*)Ash + px * 128 + off16) = v;
        }
        __syncthreads();
#pragma unroll
        for (int half = 0; half < 2; ++half) {
            int px = wave * 16 + arow;
            int kb = half * 64 + g * 16;
            bf16x8 a = *(const bf16x8*)((const char*)Ash + px * 128 + (kb ^ ((px & 7) << 4)));
            int kglob = t * 64 + half * 32 + g * 8;
#pragma unroll
            for (int n = 0; n < 14; ++n) {
                int co = n * 16 + arow;
                bf16x8 bf = *(const bf16x8*)(wB + (size_t)co * KTOT + kglob);
                acc[n] = __builtin_amdgcn_mfma_f32_16x16x32_bf16(a, bf, acc[n], 0, 0, 0);
            }
        }
    }

    int pxb = wave * 16 + g * 4;
    float* obase = om + (size_t)b * C_OM * HW + hw0 + pxb;
#pragma unroll
    for (int n = 0; n < 14; ++n) {
        int co = n * 16 + arow;
        if (co < C_OM) {
            float bias = (co < C_OFF) ? b_off[co] : b_mask[co - C_OFF];
            f32x4 r;
#pragma unroll
            for (int j = 0; j < 4; ++j) {
                float v = acc[n][j] + bias;
                if (co >= C_OFF) v = 1.f / (1.f + __expf(-v));
                r[j] = v;
            }
            *(f32x4*)(obase + (size_t)co * HW) = r;
        }
    }
}

// ---------------- DCN: (px,dg)-mapped sampling + MFMA dot ----------------
// 256 threads = (px 32, dg 8); 32-px tile, 2048 blocks. Sampling math is
// verbatim the R2/R5-validated expressions; coords computed once per
// (px,dg,tap) and shared across the group's 8 channels; k-octet q = k*8+dg
// so the 8 channels form one contiguous uv8 LDS store. Dot phase = R5's
// validated MFMA scheme with the matching wTf2 packing.

__global__ __launch_bounds__(256) void dcn_kernel3(
    const float* __restrict__ input,          // NCHW f32 (original)
    const float* __restrict__ om,
    const unsigned short* __restrict__ wTf2,  // [72][64][8] bf16
    const float* __restrict__ b_dcn,
    float* __restrict__ out)
{
    __shared__ __align__(16) unsigned short val_q[72 * 32 * 8];   // 36864 B

    int tid = threadIdx.x;
    int bid = blockIdx.x;                 // 2048
    int b   = bid >> 9;
    int hw0 = (bid & 511) << 5;           // 32-px tile, row-aligned (128%32==0)
    int ho  = hw0 >> 7;
    int wo0 = hw0 & 127;

    int px = tid & 31;
    int dg = tid >> 5;                    // 0..7

    // offsets/mask for this (px, dg): coalesced global reads (32 px per request)
    const float* omb = om + (size_t)b * C_OM * HW + hw0 + px;
    float dy[9], dx[9], mk[9];
#pragma unroll
    for (int k = 0; k < 9; ++k) {
        dy[k] = omb[(size_t)(dg * 18 + 2 * k) * HW];
        dx[k] = omb[(size_t)(dg * 18 + 2 * k + 1) * HW];
        mk[k] = omb[(size_t)(C_OFF + dg * 9 + k) * HW];
    }

    const float* plane0 = input + ((size_t)b * CIN + dg * 8) * HW;
    float yb = (float)(ho - 1);
    float xb = (float)(wo0 + px - 1);

#pragma unroll
    for (int k = 0; k < 9; ++k) {
        float ys = dy[k] + yb + (float)(k / 3);
        float xs = dx[k] + xb + (float)(k % 3);
        float y0f = floorf(ys), x0f = floorf(xs);
        float wy = ys - y0f, wx = xs - x0f;
        int y0 = (int)y0f, x0 = (int)x0f;
        bool yv0 = (unsigned)y0 < (unsigned)HH;
        bool yv1 = (unsigned)(y0 + 1) < (unsigned)HH;
        bool xv0 = (unsigned)x0 < (unsigned)WW;
        bool xv1 = (unsigned)(x0 + 1) < (unsigned)WW;
        bool m00 = yv0 && xv0, m01 = yv0 && xv1;
        bool m10 = yv1 && xv0, m11 = yv1 && xv1;
        const float* r0 = plane0 + y0 * WW + x0;
        uv8 r;
#pragma unroll
        for (int j = 0; j < 8; ++j) {
            const float* pj = r0 + (size_t)j * HW;
            float v00 = m00 ? pj[0]      : 0.f;
            float v01 = m01 ? pj[1]      : 0.f;
            float v10 = m10 ? pj[WW]     : 0.f;
            float v11 = m11 ? pj[WW + 1] : 0.f;
            float top = v00 + (v01 - v00) * wx;
            float bot = v10 + (v11 - v10) * wx;
            float v = top + (bot - top) * wy;
            r[j] = f2bf(v * mk[k]);
        }
        *(uv8*)(val_q + (k * 8 + dg) * 256 + px * 8) = r;   // contiguous 1KB/wave
    }
    __syncthreads();

    // ---- MFMA dot: wave -> (px-half h, co-half nh); 18 K-steps of 32 ----
    int lane = tid & 63, wave = tid >> 6;
    int arow = lane & 15, g = lane >> 4;
    int h  = wave & 1;
    int nh = wave >> 1;

    f32x4 acc[2];
    acc[0] = acc[1] = (f32x4){0.f, 0.f, 0.f, 0.f};
#pragma unroll
    for (int s = 0; s < 18; ++s) {
        int q = s * 4 + g;                // k-octet; kk2 = q*8 + r
        bf16x8 a = *(const bf16x8*)(val_q + q * 256 + (h * 16 + arow) * 8);
#pragma unroll
        for (int n = 0; n < 2; ++n) {
            int co = nh * 32 + n * 16 + arow;
            bf16x8 bf = *(const bf16x8*)(wTf2 + ((size_t)q * 64 + co) * 8);
            acc[n] = __builtin_amdgcn_mfma_f32_16x16x32_bf16(a, bf, acc[n], 0, 0, 0);
        }
    }

    // D: row=(lane>>4)*4+j -> px within 16-tile, col=arow -> co (validated)
#pragma unroll
    for (int n = 0; n < 2; ++n) {
        int co = nh * 32 + n * 16 + arow;
        float bias = b_dcn[co];
        f32x4 r;
#pragma unroll
        for (int j = 0; j < 4; ++j) r[j] = acc[n][j] + bias;
        *(f32x4*)(out + (size_t)b * COUT * HW + (size_t)co * HW + hw0 + h * 16 + g * 4) = r;
    }
}

// ---------------- fallback f32 kernels (if ws too small) ----------------

__global__ __launch_bounds__(256) void conv_om_kernel(
    const float* __restrict__ feature,
    const float* __restrict__ w_off, const float* __restrict__ b_off,
    const float* __restrict__ w_mask, const float* __restrict__ b_mask,
    float* __restrict__ om)
{
    int tid = threadIdx.x;
    int p = blockIdx.x * 256 + tid;
    int cg = blockIdx.y;
    int b  = p >> 14;
    int hw = p & (HW - 1);
    int ho = hw >> 7;
    int wo = hw & 127;
    int co0 = cg * 4;

    float acc[4];
    const float* wb[4];
#pragma unroll
    for (int j = 0; j < 4; ++j) {
        int co = co0 + j;
        if (co < C_OFF) { acc[j] = b_off[co];          wb[j] = w_off  + (size_t)co * 576; }
        else            { acc[j] = b_mask[co - C_OFF]; wb[j] = w_mask + (size_t)(co - C_OFF) * 576; }
    }
    const float* fb = feature + (size_t)b * CIN * HW;
    for (int ci = 0; ci < CIN; ++ci) {
        const float* fp = fb + ci * HW;
#pragma unroll
        for (int ky = 0; ky < 3; ++ky) {
            int y = ho + ky - 1;
            bool yvb = (unsigned)y < (unsigned)HH;
#pragma unroll
            for (int kx = 0; kx < 3; ++kx) {
                int x = wo + kx - 1;
                float v = (yvb && (unsigned)x < (unsigned)WW) ? fp[y * WW + x] : 0.f;
                int wi = ci * 9 + ky * 3 + kx;
#pragma unroll
                for (int j = 0; j < 4; ++j) acc[j] += v * wb[j][wi];
            }
        }
    }
    size_t obase = (size_t)b * C_OM * HW + hw;
#pragma unroll
    for (int j = 0; j < 4; ++j) {
        int co = co0 + j;
        float v = acc[j];
        if (co >= C_OFF) v = 1.f / (1.f + __expf(-v));
        om[obase + (size_t)co * HW] = v;
    }
}

__global__ __launch_bounds__(256) void dcn_kernel(
    const float* __restrict__ input,
    const float* __restrict__ om,
    const float* __restrict__ wT,
    const float* __restrict__ b_dcn,
    float* __restrict__ out)
{
    __shared__ float om_l[C_OM * 16];
    __shared__ float val_l[KTOT * 16];

    int tid  = threadIdx.x;
    int tile = blockIdx.x;
    int b    = tile >> 10;
    int hw0  = (tile & 1023) << 4;
    int ho   = hw0 >> 7;
    int wo0  = hw0 & 127;

    const float* omg = om + (size_t)b * C_OM * HW + hw0;
    for (int i = tid; i < C_OM * 16; i += 256) {
        int ch = i >> 4, px = i & 15;
        om_l[i] = omg[(size_t)ch * HW + px];
    }
    __syncthreads();

    for (int pair = tid; pair < 1024; pair += 256) {
        int px = pair & 15, c = pair >> 4;
        int dg = c >> 3;
        const float* plane = input + (size_t)(b * CIN + c) * HW;
        float yb = (float)(ho - 1);
        float xb = (float)(wo0 + px - 1);
#pragma unroll
        for (int k = 0; k < 9; ++k) {
            float dyv = om_l[(dg * 18 + 2 * k) * 16 + px];
            float dxv = om_l[(dg * 18 + 2 * k + 1) * 16 + px];
            float m  = om_l[(C_OFF + dg * 9 + k) * 16 + px];
            float ys = dyv + yb + (float)(k / 3);
            float xs = dxv + xb + (float)(k % 3);
            float y0f = floorf(ys), x0f = floorf(xs);
            float wy = ys - y0f, wx = xs - x0f;
            int y0 = (int)y0f, x0 = (int)x0f;
            bool yv0 = (unsigned)y0 < (unsigned)HH;
            bool yv1 = (unsigned)(y0 + 1) < (unsigned)HH;
            bool xv0 = (unsigned)x0 < (unsigned)WW;
            bool xv1 = (unsigned)(x0 + 1) < (unsigned)WW;
            const float* r0 = plane + y0 * WW + x0;
            float v00 = (yv0 && xv0) ? r0[0]      : 0.f;
            float v01 = (yv0 && xv1) ? r0[1]      : 0.f;
            float v10 = (yv1 && xv0) ? r0[WW]     : 0.f;
            float v11 = (yv1 && xv1) ? r0[WW + 1] : 0.f;
            float top = v00 + (v01 - v00) * wx;
            float bot = v10 + (v11 - v10) * wx;
            float v = top + (bot - top) * wy;
            val_l[(c * 9 + k) * 16 + px] = v * m;
        }
    }
    __syncthreads();

    int o2 = tid & 31;
    int ph = tid >> 5;
    int o0 = o2 * 2, px0 = ph * 2;
    float a00 = b_dcn[o0],     a01 = b_dcn[o0];
    float a10 = b_dcn[o0 + 1], a11 = b_dcn[o0 + 1];
    for (int kk = 0; kk < KTOT; ++kk) {
        float2 wv = *reinterpret_cast<const float2*>(wT + kk * 64 + o0);
        float va = val_l[kk * 16 + px0];
        float vb = val_l[kk * 16 + px0 + 1];
        a00 += wv.x * va; a01 += wv.x * vb;
        a10 += wv.y * va; a11 += wv.y * vb;
    }
    float* ob = out + (size_t)b * COUT * HW + hw0;
    ob[(size_t)o0 * HW + px0]           = a00;
    ob[(size_t)o0 * HW + px0 + 1]       = a01;
    ob[(size_t)(o0 + 1) * HW + px0]     = a10;
    ob[(size_t)(o0 + 1) * HW + px0 + 1] = a11;
}

extern "C" void kernel_launch(void* const* d_in, const int* in_sizes, int n_in,
                              void* d_out, int out_size, void* d_ws, size_t ws_size,
                              hipStream_t stream) {
    const float* input   = (const float*)d_in[0];
    const float* feature = (const float*)d_in[1];
    const float* w_off   = (const float*)d_in[2];
    const float* b_off   = (const float*)d_in[3];
    const float* w_mask  = (const float*)d_in[4];
    const float* b_mask  = (const float*)d_in[5];
    const float* w_dcn   = (const float*)d_in[6];
    const float* b_dcn   = (const float*)d_in[7];
    float* out = (float*)d_out;

    // ws layout (full path):
    float* om = (float*)d_ws;                                        // 56.62 MB
    unsigned short* fnhwc = (unsigned short*)(om + (size_t)NB * C_OM * HW); // 8.39 MB
    unsigned short* wBp   = fnhwc + (size_t)NB * HW * CIN;           // 258 KB
    unsigned short* wTfp  = wBp + (size_t)C_PAD * KTOT;              // 73.7 KB
    size_t need = (size_t)((char*)(wTfp + 72 * 64 * 8) - (char*)d_ws);

    if (ws_size >= need) {
        to_nhwc_bf16<<<NB * HW / 256, 256, 0, stream>>>(feature, fnhwc);
        prep_wB<<<(C_PAD * KTOT + 255) / 256, 256, 0, stream>>>(w_off, w_mask, wBp);
        prep_wTf2<<<(72 * 64 * 8 + 255) / 256, 256, 0, stream>>>(w_dcn, wTfp);
        conv_om_mfma<<<NB * HW / 64, 256, 0, stream>>>(fnhwc, wBp, b_off, b_mask, om);
        dcn_kernel3<<<NB * HW / 32, 256, 0, stream>>>(input, om, wTfp, b_dcn, out);
    } else {
        // fallback: pure f32 path (R1-validated)
        float* wT = om + (size_t)NB * C_OM * HW;
        transpose_wdcn<<<(KTOT * COUT + 255) / 256, 256, 0, stream>>>(w_dcn, wT);
        dim3 cgrid(NB * HW / 256, 54);
        conv_om_kernel<<<cgrid, 256, 0, stream>>>(feature, w_off, b_off, w_mask, b_mask, om);
        dcn_kernel<<<NB * HW / 16, 256, 0, stream>>>(input, om, wT, b_dcn, out);
    }
}

// Round 7
// 201.058 us; speedup vs baseline: 4.0495x; 1.3468x over previous
//
#include <hip/hip_runtime.h>
#include <hip/hip_bf16.h>

#define NB 4
#define CIN 64
#define COUT 64
#define HH 128
#define WW 128
#define HW (HH*WW)
#define C_OFF 144
#define C_OM 216
#define C_PAD 224
#define KTOT 576   // CIN * 9

typedef __attribute__((ext_vector_type(8))) short bf16x8;
typedef __attribute__((ext_vector_type(4))) float f32x4;
typedef __attribute__((ext_vector_type(8))) unsigned short uv8;

__device__ inline unsigned short f2bf(float f) {
    union { float f; unsigned u; } v; v.f = f;
    unsigned r = (v.u + 0x7FFF + ((v.u >> 16) & 1)) >> 16;   // RNE
    return (unsigned short)r;
}

__device__ inline float bf2f(unsigned short h) {
    union { unsigned u; float f; } v; v.u = ((unsigned)h) << 16; return v.f;
}

// ---------------- prep kernels ----------------

__global__ __launch_bounds__(256) void transpose_wdcn(const float* __restrict__ w,
                                                      float* __restrict__ wT) {
    int idx = blockIdx.x * 256 + threadIdx.x;
    if (idx < KTOT * COUT) {
        int o = idx & 63, kk = idx >> 6;
        wT[idx] = w[o * KTOT + kk];
    }
}

// [b][c 64][y][x] f32 -> [b][y][x][c 64] bf16  (validated: feeds conv_om_mfma)
__global__ __launch_bounds__(256) void to_nhwc_bf16(const float* __restrict__ f,
                                                    unsigned short* __restrict__ o) {
    int t = blockIdx.x * 256 + threadIdx.x;      // 65536 = NB*HW
    int b = t >> 14, yx = t & 16383;
    const float* src = f + (size_t)b * CIN * HW + yx;
    unsigned short* dst = o + (size_t)t * 64;
#pragma unroll
    for (int c8 = 0; c8 < 8; ++c8) {
        uv8 v;
#pragma unroll
        for (int j = 0; j < 8; ++j) v[j] = f2bf(src[(size_t)(c8 * 8 + j) * HW]);
        *(uv8*)(dst + c8 * 8) = v;
    }
}

// wB[co][t*64+ci] bf16, co in [0,224), zeros for co>=216
__global__ __launch_bounds__(256) void prep_wB(const float* __restrict__ w_off,
                                               const float* __restrict__ w_mask,
                                               unsigned short* __restrict__ wB) {
    int idx = blockIdx.x * 256 + threadIdx.x;    // 224*576
    if (idx >= C_PAD * KTOT) return;
    int co = idx / KTOT, k = idx - co * KTOT;
    int t = k >> 6, ci = k & 63;
    float v = 0.f;
    if (co < C_OFF)      v = w_off[(size_t)co * KTOT + ci * 9 + t];
    else if (co < C_OM)  v = w_mask[(size_t)(co - C_OFF) * KTOT + ci * 9 + t];
    wB[idx] = f2bf(v);
}

// wTf2[q][co][r] bf16 = w_dcn[co][(dg*8+r)*9 + k], q = k*8+dg  (kk2 = tap*64+c order)
__global__ __launch_bounds__(256) void prep_wTf2(const float* __restrict__ w,
                                                 unsigned short* __restrict__ wTf2) {
    int idx = blockIdx.x * 256 + threadIdx.x;    // 72*64*8 = 36864
    if (idx >= 72 * 64 * 8) return;
    int q = idx >> 9;
    int co = (idx >> 3) & 63;
    int r = idx & 7;
    int k = q >> 3, dg = q & 7;
    wTf2[idx] = f2bf(w[(size_t)co * KTOT + (dg * 8 + r) * 9 + k]);
}

// ---------------- MFMA implicit-GEMM conv for offset+mask (validated R2) ----------------

__global__ __launch_bounds__(256, 4) void conv_om_mfma(
    const unsigned short* __restrict__ fnhwc,
    const unsigned short* __restrict__ wB,
    const float* __restrict__ b_off, const float* __restrict__ b_mask,
    float* __restrict__ om)
{
    __shared__ __align__(16) unsigned short Ash[64 * 64];

    int tid = threadIdx.x;
    int bid = blockIdx.x;
    int b   = bid >> 8;
    int hw0 = (bid & 255) << 6;
    int ho  = hw0 >> 7;
    int wo0 = hw0 & 127;
    int lane = tid & 63, wave = tid >> 6;
    int arow = lane & 15;
    int g    = lane >> 4;

    f32x4 acc[14];
#pragma unroll
    for (int n = 0; n < 14; ++n) acc[n] = (f32x4){0.f, 0.f, 0.f, 0.f};

    int px_w = tid >> 3;
    int c8_w = tid & 7;

    for (int t = 0; t < 9; ++t) {
        int ky = t / 3, kx = t - ky * 3;
        int y = ho + ky - 1;
        bool yv = (unsigned)y < (unsigned)HH;
        __syncthreads();
#pragma unroll
        for (int rep = 0; rep < 2; ++rep) {
            int px = px_w + rep * 32;
            int x = wo0 + px + kx - 1;
            uv8 v = (uv8){0, 0, 0, 0, 0, 0, 0, 0};
            if (yv && (unsigned)x < (unsigned)WW)
                v = *(const uv8*)(fnhwc + ((size_t)((b * HH + y) * WW + x) << 6) + c8_w * 8);
            int off16 = (c8_w << 4) ^ ((px & 7) << 4);
            *(uv8*)((char*)Ash + px * 128 + off16) = v;
        }
        __syncthreads();
#pragma unroll
        for (int half = 0; half < 2; ++half) {
            int px = wave * 16 + arow;
            int kb = half * 64 + g * 16;
            bf16x8 a = *(const bf16x8*)((const char*)Ash + px * 128 + (kb ^ ((px & 7) << 4)));
            int kglob = t * 64 + half * 32 + g * 8;
#pragma unroll
            for (int n = 0; n < 14; ++n) {
                int co = n * 16 + arow;
                bf16x8 bf = *(const bf16x8*)(wB + (size_t)co * KTOT + kglob);
                acc[n] = __builtin_amdgcn_mfma_f32_16x16x32_bf16(a, bf, acc[n], 0, 0, 0);
            }
        }
    }

    int pxb = wave * 16 + g * 4;
    float* obase = om + (size_t)b * C_OM * HW + hw0 + pxb;
#pragma unroll
    for (int n = 0; n < 14; ++n) {
        int co = n * 16 + arow;
        if (co < C_OM) {
            float bias = (co < C_OFF) ? b_off[co] : b_mask[co - C_OFF];
            f32x4 r;
#pragma unroll
            for (int j = 0; j < 4; ++j) {
                float v = acc[n][j] + bias;
                if (co >= C_OFF) v = 1.f / (1.f + __expf(-v));
                r[j] = v;
            }
            *(f32x4*)(obase + (size_t)co * HW) = r;
        }
    }
}

// ---------------- DCN: (px,dg)-mapped sampling + MFMA dot ----------------
// R6-validated structure. Single change this round: input gathers read the
// NHWC bf16 transpose (4x guarded 16B loads per tap) instead of 32 scalar
// NCHW f32 loads. Transpose produced by the validated to_nhwc_bf16 kernel.

__global__ __launch_bounds__(256) void dcn_kernel3(
    const unsigned short* __restrict__ inb,   // [b][y][x][c 64] bf16
    const float* __restrict__ om,
    const unsigned short* __restrict__ wTf2,  // [72][64][8] bf16
    const float* __restrict__ b_dcn,
    float* __restrict__ out)
{
    __shared__ __align__(16) unsigned short val_q[72 * 32 * 8];   // 36864 B

    int tid = threadIdx.x;
    int bid = blockIdx.x;                 // 2048
    int b   = bid >> 9;
    int hw0 = (bid & 511) << 5;           // 32-px tile, row-aligned (128%32==0)
    int ho  = hw0 >> 7;
    int wo0 = hw0 & 127;

    int px = tid & 31;
    int dg = tid >> 5;                    // 0..7

    // offsets/mask for this (px, dg): coalesced global reads (32 px per request)
    const float* omb = om + (size_t)b * C_OM * HW + hw0 + px;
    float dy[9], dx[9], mk[9];
#pragma unroll
    for (int k = 0; k < 9; ++k) {
        dy[k] = omb[(size_t)(dg * 18 + 2 * k) * HW];
        dx[k] = omb[(size_t)(dg * 18 + 2 * k + 1) * HW];
        mk[k] = omb[(size_t)(C_OFF + dg * 9 + k) * HW];
    }

    const unsigned short* plane0 = inb + ((size_t)b * HW << 6) + dg * 8;
    float yb = (float)(ho - 1);
    float xb = (float)(wo0 + px - 1);

#pragma unroll
    for (int k = 0; k < 9; ++k) {
        float ys = dy[k] + yb + (float)(k / 3);
        float xs = dx[k] + xb + (float)(k % 3);
        float y0f = floorf(ys), x0f = floorf(xs);
        float fy = ys - y0f, fx = xs - x0f;
        int y0 = (int)y0f, x0 = (int)x0f;
        bool yv0 = (unsigned)y0 < (unsigned)HH;
        bool yv1 = (unsigned)(y0 + 1) < (unsigned)HH;
        bool xv0 = (unsigned)x0 < (unsigned)WW;
        bool xv1 = (unsigned)(x0 + 1) < (unsigned)WW;
        const unsigned short* pp = plane0 + (y0 * WW + x0) * 64;
        uv8 c00 = (uv8){0,0,0,0,0,0,0,0};
        uv8 c01 = c00, c10 = c00, c11 = c00;
        if (yv0 && xv0) c00 = *(const uv8*)(pp);
        if (yv0 && xv1) c01 = *(const uv8*)(pp + 64);
        if (yv1 && xv0) c10 = *(const uv8*)(pp + 64 * WW);
        if (yv1 && xv1) c11 = *(const uv8*)(pp + 64 * WW + 64);
        uv8 r;
#pragma unroll
        for (int j = 0; j < 8; ++j) {
            float v00 = bf2f(c00[j]), v01 = bf2f(c01[j]);
            float v10 = bf2f(c10[j]), v11 = bf2f(c11[j]);
            float top = v00 + (v01 - v00) * fx;
            float bot = v10 + (v11 - v10) * fx;
            float v = top + (bot - top) * fy;
            r[j] = f2bf(v * mk[k]);
        }
        *(uv8*)(val_q + (k * 8 + dg) * 256 + px * 8) = r;   // contiguous 1KB/wave
    }
    __syncthreads();

    // ---- MFMA dot: wave -> (px-half h, co-half nh); 18 K-steps of 32 ----
    int lane = tid & 63, wave = tid >> 6;
    int arow = lane & 15, g = lane >> 4;
    int h  = wave & 1;
    int nh = wave >> 1;

    f32x4 acc[2];
    acc[0] = acc[1] = (f32x4){0.f, 0.f, 0.f, 0.f};
#pragma unroll
    for (int s = 0; s < 18; ++s) {
        int q = s * 4 + g;                // k-octet; kk2 = q*8 + r
        bf16x8 a = *(const bf16x8*)(val_q + q * 256 + (h * 16 + arow) * 8);
#pragma unroll
        for (int n = 0; n < 2; ++n) {
            int co = nh * 32 + n * 16 + arow;
            bf16x8 bf = *(const bf16x8*)(wTf2 + ((size_t)q * 64 + co) * 8);
            acc[n] = __builtin_amdgcn_mfma_f32_16x16x32_bf16(a, bf, acc[n], 0, 0, 0);
        }
    }

    // D: row=(lane>>4)*4+j -> px within 16-tile, col=arow -> co (validated)
#pragma unroll
    for (int n = 0; n < 2; ++n) {
        int co = nh * 32 + n * 16 + arow;
        float bias = b_dcn[co];
        f32x4 r;
#pragma unroll
        for (int j = 0; j < 4; ++j) r[j] = acc[n][j] + bias;
        *(f32x4*)(out + (size_t)b * COUT * HW + (size_t)co * HW + hw0 + h * 16 + g * 4) = r;
    }
}

// ---------------- fallback f32 kernels (if ws too small) ----------------

__global__ __launch_bounds__(256) void conv_om_kernel(
    const float* __restrict__ feature,
    const float* __restrict__ w_off, const float* __restrict__ b_off,
    const float* __restrict__ w_mask, const float* __restrict__ b_mask,
    float* __restrict__ om)
{
    int tid = threadIdx.x;
    int p = blockIdx.x * 256 + tid;
    int cg = blockIdx.y;
    int b  = p >> 14;
    int hw = p & (HW - 1);
    int ho = hw >> 7;
    int wo = hw & 127;
    int co0 = cg * 4;

    float acc[4];
    const float* wb[4];
#pragma unroll
    for (int j = 0; j < 4; ++j) {
        int co = co0 + j;
        if (co < C_OFF) { acc[j] = b_off[co];          wb[j] = w_off  + (size_t)co * 576; }
        else            { acc[j] = b_mask[co - C_OFF]; wb[j] = w_mask + (size_t)(co - C_OFF) * 576; }
    }
    const float* fb = feature + (size_t)b * CIN * HW;
    for (int ci = 0; ci < CIN; ++ci) {
        const float* fp = fb + ci * HW;
#pragma unroll
        for (int ky = 0; ky < 3; ++ky) {
            int y = ho + ky - 1;
            bool yvb = (unsigned)y < (unsigned)HH;
#pragma unroll
            for (int kx = 0; kx < 3; ++kx) {
                int x = wo + kx - 1;
                float v = (yvb && (unsigned)x < (unsigned)WW) ? fp[y * WW + x] : 0.f;
                int wi = ci * 9 + ky * 3 + kx;
#pragma unroll
                for (int j = 0; j < 4; ++j) acc[j] += v * wb[j][wi];
            }
        }
    }
    size_t obase = (size_t)b * C_OM * HW + hw;
#pragma unroll
    for (int j = 0; j < 4; ++j) {
        int co = co0 + j;
        float v = acc[j];
        if (co >= C_OFF) v = 1.f / (1.f + __expf(-v));
        om[obase + (size_t)co * HW] = v;
    }
}

__global__ __launch_bounds__(256) void dcn_kernel(
    const float* __restrict__ input,
    const float* __restrict__ om,
    const float* __restrict__ wT,
    const float* __restrict__ b_dcn,
    float* __restrict__ out)
{
    __shared__ float om_l[C_OM * 16];
    __shared__ float val_l[KTOT * 16];

    int tid  = threadIdx.x;
    int tile = blockIdx.x;
    int b    = tile >> 10;
    int hw0  = (tile & 1023) << 4;
    int ho   = hw0 >> 7;
    int wo0  = hw0 & 127;

    const float* omg = om + (size_t)b * C_OM * HW + hw0;
    for (int i = tid; i < C_OM * 16; i += 256) {
        int ch = i >> 4, px = i & 15;
        om_l[i] = omg[(size_t)ch * HW + px];
    }
    __syncthreads();

    for (int pair = tid; pair < 1024; pair += 256) {
        int px = pair & 15, c = pair >> 4;
        int dg = c >> 3;
        const float* plane = input + (size_t)(b * CIN + c) * HW;
        float yb = (float)(ho - 1);
        float xb = (float)(wo0 + px - 1);
#pragma unroll
        for (int k = 0; k < 9; ++k) {
            float dyv = om_l[(dg * 18 + 2 * k) * 16 + px];
            float dxv = om_l[(dg * 18 + 2 * k + 1) * 16 + px];
            float m  = om_l[(C_OFF + dg * 9 + k) * 16 + px];
            float ys = dyv + yb + (float)(k / 3);
            float xs = dxv + xb + (float)(k % 3);
            float y0f = floorf(ys), x0f = floorf(xs);
            float wy = ys - y0f, wx = xs - x0f;
            int y0 = (int)y0f, x0 = (int)x0f;
            bool yv0 = (unsigned)y0 < (unsigned)HH;
            bool yv1 = (unsigned)(y0 + 1) < (unsigned)HH;
            bool xv0 = (unsigned)x0 < (unsigned)WW;
            bool xv1 = (unsigned)(x0 + 1) < (unsigned)WW;
            const float* r0 = plane + y0 * WW + x0;
            float v00 = (yv0 && xv0) ? r0[0]      : 0.f;
            float v01 = (yv0 && xv1) ? r0[1]      : 0.f;
            float v10 = (yv1 && xv0) ? r0[WW]     : 0.f;
            float v11 = (yv1 && xv1) ? r0[WW + 1] : 0.f;
            float top = v00 + (v01 - v00) * wx;
            float bot = v10 + (v11 - v10) * wx;
            float v = top + (bot - top) * wy;
            val_l[(c * 9 + k) * 16 + px] = v * m;
        }
    }
    __syncthreads();

    int o2 = tid & 31;
    int ph = tid >> 5;
    int o0 = o2 * 2, px0 = ph * 2;
    float a00 = b_dcn[o0],     a01 = b_dcn[o0];
    float a10 = b_dcn[o0 + 1], a11 = b_dcn[o0 + 1];
    for (int kk = 0; kk < KTOT; ++kk) {
        float2 wv = *reinterpret_cast<const float2*>(wT + kk * 64 + o0);
        float va = val_l[kk * 16 + px0];
        float vb = val_l[kk * 16 + px0 + 1];
        a00 += wv.x * va; a01 += wv.x * vb;
        a10 += wv.y * va; a11 += wv.y * vb;
    }
    float* ob = out + (size_t)b * COUT * HW + hw0;
    ob[(size_t)o0 * HW + px0]           = a00;
    ob[(size_t)o0 * HW + px0 + 1]       = a01;
    ob[(size_t)(o0 + 1) * HW + px0]     = a10;
    ob[(size_t)(o0 + 1) * HW + px0 + 1] = a11;
}

extern "C" void kernel_launch(void* const* d_in, const int* in_sizes, int n_in,
                              void* d_out, int out_size, void* d_ws, size_t ws_size,
                              hipStream_t stream) {
    const float* input   = (const float*)d_in[0];
    const float* feature = (const float*)d_in[1];
    const float* w_off   = (const float*)d_in[2];
    const float* b_off   = (const float*)d_in[3];
    const float* w_mask  = (const float*)d_in[4];
    const float* b_mask  = (const float*)d_in[5];
    const float* w_dcn   = (const float*)d_in[6];
    const float* b_dcn   = (const float*)d_in[7];
    float* out = (float*)d_out;

    // ws layout (full path):
    float* om = (float*)d_ws;                                        // 56.62 MB
    unsigned short* fnhwc = (unsigned short*)(om + (size_t)NB * C_OM * HW); // 8.39 MB
    unsigned short* wBp   = fnhwc + (size_t)NB * HW * CIN;           // 258 KB
    unsigned short* wTfp  = wBp + (size_t)C_PAD * KTOT;              // 73.7 KB
    unsigned short* inb   = wTfp + 72 * 64 * 8;                      // 8.39 MB (input NHWC bf16)
    size_t need = (size_t)((char*)(inb + (size_t)NB * HW * CIN) - (char*)d_ws);

    if (ws_size >= need) {
        to_nhwc_bf16<<<NB * HW / 256, 256, 0, stream>>>(feature, fnhwc);
        to_nhwc_bf16<<<NB * HW / 256, 256, 0, stream>>>(input, inb);
        prep_wB<<<(C_PAD * KTOT + 255) / 256, 256, 0, stream>>>(w_off, w_mask, wBp);
        prep_wTf2<<<(72 * 64 * 8 + 255) / 256, 256, 0, stream>>>(w_dcn, wTfp);
        conv_om_mfma<<<NB * HW / 64, 256, 0, stream>>>(fnhwc, wBp, b_off, b_mask, om);
        dcn_kernel3<<<NB * HW / 32, 256, 0, stream>>>(inb, om, wTfp, b_dcn, out);
    } else {
        // fallback: pure f32 path (R1-validated)
        float* wT = om + (size_t)NB * C_OM * HW;
        transpose_wdcn<<<(KTOT * COUT + 255) / 256, 256, 0, stream>>>(w_dcn, wT);
        dim3 cgrid(NB * HW / 256, 54);
        conv_om_kernel<<<cgrid, 256, 0, stream>>>(feature, w_off, b_off, w_mask, b_mask, om);
        dcn_kernel<<<NB * HW / 16, 256, 0, stream>>>(input, om, wT, b_dcn, out);
    }
}

// Round 8
// 192.424 us; speedup vs baseline: 4.2312x; 1.0449x over previous
//
#include <hip/hip_runtime.h>
#include <hip/hip_bf16.h>

#define NB 4
#define CIN 64
#define COUT 64
#define HH 128
#define WW 128
#define HW (HH*WW)
#define C_OFF 144
#define C_OM 216
#define C_PAD 224
#define KTOT 576   // CIN * 9

typedef __attribute__((ext_vector_type(8))) short bf16x8;
typedef __attribute__((ext_vector_type(4))) float f32x4;
typedef __attribute__((ext_vector_type(8))) unsigned short uv8;

__device__ inline unsigned short f2bf(float f) {
    union { float f; unsigned u; } v; v.f = f;
    unsigned r = (v.u + 0x7FFF + ((v.u >> 16) & 1)) >> 16;   // RNE
    return (unsigned short)r;
}

__device__ inline float bf2f(unsigned short h) {
    union { unsigned u; float f; } v; v.u = ((unsigned)h) << 16; return v.f;
}

// ---------------- prep kernels (all validated) ----------------

__global__ __launch_bounds__(256) void transpose_wdcn(const float* __restrict__ w,
                                                      float* __restrict__ wT) {
    int idx = blockIdx.x * 256 + threadIdx.x;
    if (idx < KTOT * COUT) {
        int o = idx & 63, kk = idx >> 6;
        wT[idx] = w[o * KTOT + kk];
    }
}

// [b][c 64][y][x] f32 -> [b][y][x][c 64] bf16
__global__ __launch_bounds__(256) void to_nhwc_bf16(const float* __restrict__ f,
                                                    unsigned short* __restrict__ o) {
    int t = blockIdx.x * 256 + threadIdx.x;      // 65536 = NB*HW
    int b = t >> 14, yx = t & 16383;
    const float* src = f + (size_t)b * CIN * HW + yx;
    unsigned short* dst = o + (size_t)t * 64;
#pragma unroll
    for (int c8 = 0; c8 < 8; ++c8) {
        uv8 v;
#pragma unroll
        for (int j = 0; j < 8; ++j) v[j] = f2bf(src[(size_t)(c8 * 8 + j) * HW]);
        *(uv8*)(dst + c8 * 8) = v;
    }
}

// wB[co][t*64+ci] bf16, co in [0,224), zeros for co>=216
__global__ __launch_bounds__(256) void prep_wB(const float* __restrict__ w_off,
                                               const float* __restrict__ w_mask,
                                               unsigned short* __restrict__ wB) {
    int idx = blockIdx.x * 256 + threadIdx.x;    // 224*576
    if (idx >= C_PAD * KTOT) return;
    int co = idx / KTOT, k = idx - co * KTOT;
    int t = k >> 6, ci = k & 63;
    float v = 0.f;
    if (co < C_OFF)      v = w_off[(size_t)co * KTOT + ci * 9 + t];
    else if (co < C_OM)  v = w_mask[(size_t)(co - C_OFF) * KTOT + ci * 9 + t];
    wB[idx] = f2bf(v);
}

// wTf2[q][co][r] bf16 = w_dcn[co][(dg*8+r)*9 + k], q = k*8+dg
__global__ __launch_bounds__(256) void prep_wTf2(const float* __restrict__ w,
                                                 unsigned short* __restrict__ wTf2) {
    int idx = blockIdx.x * 256 + threadIdx.x;    // 72*64*8 = 36864
    if (idx >= 72 * 64 * 8) return;
    int q = idx >> 9;
    int co = (idx >> 3) & 63;
    int r = idx & 7;
    int k = q >> 3, dg = q & 7;
    wTf2[idx] = f2bf(w[(size_t)co * KTOT + (dg * 8 + r) * 9 + k]);
}

// ---------------- fused: conv(offset+mask) -> LDS -> sampling -> dot ----------------
// 256 threads, 32-px tile, 2048 blocks. Conv phase = validated conv_om_mfma
// structure at half tile width (per-wave 16px x 112co); epilogue lands in
// om_l (LDS, pad-33 stride). Sampling + dot phases = verbatim R7 dcn_kernel3
// with om reads redirected to om_l. val_q aliases the conv staging buffer
// (conv Ash reads all complete before the post-epilogue barrier).

__global__ __launch_bounds__(256, 2) void dcn_fused(
    const unsigned short* __restrict__ fnhwc,  // feature NHWC bf16
    const unsigned short* __restrict__ inb,    // input NHWC bf16
    const unsigned short* __restrict__ wB,     // [224][576] bf16
    const unsigned short* __restrict__ wTf2,   // [72][64][8] bf16
    const float* __restrict__ b_off, const float* __restrict__ b_mask,
    const float* __restrict__ b_dcn,
    float* __restrict__ out)
{
    __shared__ float om_l[C_PAD * 33];                          // 29568 B
    __shared__ __align__(16) unsigned short val_q[72 * 32 * 8]; // 36864 B
    unsigned short* Ash = val_q;                                // conv staging alias (4 KB)

    int tid = threadIdx.x;
    int bid = blockIdx.x;                 // 2048
    int b   = bid >> 9;
    int hw0 = (bid & 511) << 5;           // 32-px tile, row-aligned
    int ho  = hw0 >> 7;
    int wo0 = hw0 & 127;

    int lane = tid & 63, wave = tid >> 6;
    int arow = lane & 15, g = lane >> 4;
    int h  = wave & 1;                    // px 16-half
    int ws = wave >> 1;                   // co 112-half

    // ---- conv phase ----
    f32x4 acc[7];
#pragma unroll
    for (int n = 0; n < 7; ++n) acc[n] = (f32x4){0.f, 0.f, 0.f, 0.f};

    int px_w = tid >> 3;                  // 0..31
    int c8_w = tid & 7;

    for (int t = 0; t < 9; ++t) {
        int ky = t / 3, kx = t - ky * 3;
        int y = ho + ky - 1;
        bool yv = (unsigned)y < (unsigned)HH;
        __syncthreads();
        {
            int x = wo0 + px_w + kx - 1;
            uv8 v = (uv8){0, 0, 0, 0, 0, 0, 0, 0};
            if (yv && (unsigned)x < (unsigned)WW)
                v = *(const uv8*)(fnhwc + ((size_t)((b * HH + y) * WW + x) << 6) + c8_w * 8);
            int off16 = (c8_w << 4) ^ ((px_w & 7) << 4);
            *(uv8*)((char*)Ash + px_w * 128 + off16) = v;
        }
        __syncthreads();
#pragma unroll
        for (int half = 0; half < 2; ++half) {
            int px = h * 16 + arow;
            int kb = half * 64 + g * 16;
            bf16x8 a = *(const bf16x8*)((const char*)Ash + px * 128 + (kb ^ ((px & 7) << 4)));
            int kglob = t * 64 + half * 32 + g * 8;
#pragma unroll
            for (int n = 0; n < 7; ++n) {
                int co = ws * 112 + n * 16 + arow;
                bf16x8 bf = *(const bf16x8*)(wB + (size_t)co * KTOT + kglob);
                acc[n] = __builtin_amdgcn_mfma_f32_16x16x32_bf16(a, bf, acc[n], 0, 0, 0);
            }
        }
    }

    // conv epilogue -> om_l (bias + sigmoid for mask channels)
#pragma unroll
    for (int n = 0; n < 7; ++n) {
        int co = ws * 112 + n * 16 + arow;
        if (co < C_OM) {
            float bias = (co < C_OFF) ? b_off[co] : b_mask[co - C_OFF];
#pragma unroll
            for (int j = 0; j < 4; ++j) {
                float v = acc[n][j] + bias;
                if (co >= C_OFF) v = 1.f / (1.f + __expf(-v));
                om_l[co * 33 + h * 16 + g * 4 + j] = v;
            }
        }
    }
    __syncthreads();

    // ---- sampling phase (verbatim R7, om from om_l) ----
    int px = tid & 31;
    int dg = tid >> 5;                    // 0..7

    float dy[9], dxv[9], mk[9];
#pragma unroll
    for (int k = 0; k < 9; ++k) {
        dy[k]  = om_l[(dg * 18 + 2 * k) * 33 + px];
        dxv[k] = om_l[(dg * 18 + 2 * k + 1) * 33 + px];
        mk[k]  = om_l[(C_OFF + dg * 9 + k) * 33 + px];
    }

    const unsigned short* plane0 = inb + ((size_t)b * HW << 6) + dg * 8;
    float yb = (float)(ho - 1);
    float xb = (float)(wo0 + px - 1);

#pragma unroll
    for (int k = 0; k < 9; ++k) {
        float ys = dy[k] + yb + (float)(k / 3);
        float xs = dxv[k] + xb + (float)(k % 3);
        float y0f = floorf(ys), x0f = floorf(xs);
        float fy = ys - y0f, fx = xs - x0f;
        int y0 = (int)y0f, x0 = (int)x0f;
        bool yv0 = (unsigned)y0 < (unsigned)HH;
        bool yv1 = (unsigned)(y0 + 1) < (unsigned)HH;
        bool xv0 = (unsigned)x0 < (unsigned)WW;
        bool xv1 = (unsigned)(x0 + 1) < (unsigned)WW;
        const unsigned short* pp = plane0 + (y0 * WW + x0) * 64;
        uv8 c00 = (uv8){0,0,0,0,0,0,0,0};
        uv8 c01 = c00, c10 = c00, c11 = c00;
        if (yv0 && xv0) c00 = *(const uv8*)(pp);
        if (yv0 && xv1) c01 = *(const uv8*)(pp + 64);
        if (yv1 && xv0) c10 = *(const uv8*)(pp + 64 * WW);
        if (yv1 && xv1) c11 = *(const uv8*)(pp + 64 * WW + 64);
        uv8 r;
#pragma unroll
        for (int j = 0; j < 8; ++j) {
            float v00 = bf2f(c00[j]), v01 = bf2f(c01[j]);
            float v10 = bf2f(c10[j]), v11 = bf2f(c11[j]);
            float top = v00 + (v01 - v00) * fx;
            float bot = v10 + (v11 - v10) * fx;
            float v = top + (bot - top) * fy;
            r[j] = f2bf(v * mk[k]);
        }
        *(uv8*)(val_q + (k * 8 + dg) * 256 + px * 8) = r;
    }
    __syncthreads();

    // ---- dot phase (verbatim R7) ----
    int nh = wave >> 1;

    f32x4 dacc[2];
    dacc[0] = dacc[1] = (f32x4){0.f, 0.f, 0.f, 0.f};
#pragma unroll
    for (int s = 0; s < 18; ++s) {
        int q = s * 4 + g;
        bf16x8 a = *(const bf16x8*)(val_q + q * 256 + (h * 16 + arow) * 8);
#pragma unroll
        for (int n = 0; n < 2; ++n) {
            int co = nh * 32 + n * 16 + arow;
            bf16x8 bf = *(const bf16x8*)(wTf2 + ((size_t)q * 64 + co) * 8);
            dacc[n] = __builtin_amdgcn_mfma_f32_16x16x32_bf16(a, bf, dacc[n], 0, 0, 0);
        }
    }

#pragma unroll
    for (int n = 0; n < 2; ++n) {
        int co = nh * 32 + n * 16 + arow;
        float bias = b_dcn[co];
        f32x4 r;
#pragma unroll
        for (int j = 0; j < 4; ++j) r[j] = dacc[n][j] + bias;
        *(f32x4*)(out + (size_t)b * COUT * HW + (size_t)co * HW + hw0 + h * 16 + g * 4) = r;
    }
}

// ---------------- fallback f32 kernels (if ws too small) ----------------

__global__ __launch_bounds__(256) void conv_om_kernel(
    const float* __restrict__ feature,
    const float* __restrict__ w_off, const float* __restrict__ b_off,
    const float* __restrict__ w_mask, const float* __restrict__ b_mask,
    float* __restrict__ om)
{
    int tid = threadIdx.x;
    int p = blockIdx.x * 256 + tid;
    int cg = blockIdx.y;
    int b  = p >> 14;
    int hw = p & (HW - 1);
    int ho = hw >> 7;
    int wo = hw & 127;
    int co0 = cg * 4;

    float acc[4];
    const float* wb[4];
#pragma unroll
    for (int j = 0; j < 4; ++j) {
        int co = co0 + j;
        if (co < C_OFF) { acc[j] = b_off[co];          wb[j] = w_off  + (size_t)co * 576; }
        else            { acc[j] = b_mask[co - C_OFF]; wb[j] = w_mask + (size_t)(co - C_OFF) * 576; }
    }
    const float* fb = feature + (size_t)b * CIN * HW;
    for (int ci = 0; ci < CIN; ++ci) {
        const float* fp = fb + ci * HW;
#pragma unroll
        for (int ky = 0; ky < 3; ++ky) {
            int y = ho + ky - 1;
            bool yvb = (unsigned)y < (unsigned)HH;
#pragma unroll
            for (int kx = 0; kx < 3; ++kx) {
                int x = wo + kx - 1;
                float v = (yvb && (unsigned)x < (unsigned)WW) ? fp[y * WW + x] : 0.f;
                int wi = ci * 9 + ky * 3 + kx;
#pragma unroll
                for (int j = 0; j < 4; ++j) acc[j] += v * wb[j][wi];
            }
        }
    }
    size_t obase = (size_t)b * C_OM * HW + hw;
#pragma unroll
    for (int j = 0; j < 4; ++j) {
        int co = co0 + j;
        float v = acc[j];
        if (co >= C_OFF) v = 1.f / (1.f + __expf(-v));
        om[obase + (size_t)co * HW] = v;
    }
}

__global__ __launch_bounds__(256) void dcn_kernel(
    const float* __restrict__ input,
    const float* __restrict__ om,
    const float* __restrict__ wT,
    const float* __restrict__ b_dcn,
    float* __restrict__ out)
{
    __shared__ float om_l[C_OM * 16];
    __shared__ float val_l[KTOT * 16];

    int tid  = threadIdx.x;
    int tile = blockIdx.x;
    int b    = tile >> 10;
    int hw0  = (tile & 1023) << 4;
    int ho   = hw0 >> 7;
    int wo0  = hw0 & 127;

    const float* omg = om + (size_t)b * C_OM * HW + hw0;
    for (int i = tid; i < C_OM * 16; i += 256) {
        int ch = i >> 4, px = i & 15;
        om_l[i] = omg[(size_t)ch * HW + px];
    }
    __syncthreads();

    for (int pair = tid; pair < 1024; pair += 256) {
        int px = pair & 15, c = pair >> 4;
        int dg = c >> 3;
        const float* plane = input + (size_t)(b * CIN + c) * HW;
        float yb = (float)(ho - 1);
        float xb = (float)(wo0 + px - 1);
#pragma unroll
        for (int k = 0; k < 9; ++k) {
            float dyv = om_l[(dg * 18 + 2 * k) * 16 + px];
            float dxv = om_l[(dg * 18 + 2 * k + 1) * 16 + px];
            float m  = om_l[(C_OFF + dg * 9 + k) * 16 + px];
            float ys = dyv + yb + (float)(k / 3);
            float xs = dxv + xb + (float)(k % 3);
            float y0f = floorf(ys), x0f = floorf(xs);
            float wy = ys - y0f, wx = xs - x0f;
            int y0 = (int)y0f, x0 = (int)x0f;
            bool yv0 = (unsigned)y0 < (unsigned)HH;
            bool yv1 = (unsigned)(y0 + 1) < (unsigned)HH;
            bool xv0 = (unsigned)x0 < (unsigned)WW;
            bool xv1 = (unsigned)(x0 + 1) < (unsigned)WW;
            const float* r0 = plane + y0 * WW + x0;
            float v00 = (yv0 && xv0) ? r0[0]      : 0.f;
            float v01 = (yv0 && xv1) ? r0[1]      : 0.f;
            float v10 = (yv1 && xv0) ? r0[WW]     : 0.f;
            float v11 = (yv1 && xv1) ? r0[WW + 1] : 0.f;
            float top = v00 + (v01 - v00) * wx;
            float bot = v10 + (v11 - v10) * wx;
            float v = top + (bot - top) * wy;
            val_l[(c * 9 + k) * 16 + px] = v * m;
        }
    }
    __syncthreads();

    int o2 = tid & 31;
    int ph = tid >> 5;
    int o0 = o2 * 2, px0 = ph * 2;
    float a00 = b_dcn[o0],     a01 = b_dcn[o0];
    float a10 = b_dcn[o0 + 1], a11 = b_dcn[o0 + 1];
    for (int kk = 0; kk < KTOT; ++kk) {
        float2 wv = *reinterpret_cast<const float2*>(wT + kk * 64 + o0);
        float va = val_l[kk * 16 + px0];
        float vb = val_l[kk * 16 + px0 + 1];
        a00 += wv.x * va; a01 += wv.x * vb;
        a10 += wv.y * va; a11 += wv.y * vb;
    }
    float* ob = out + (size_t)b * COUT * HW + hw0;
    ob[(size_t)o0 * HW + px0]           = a00;
    ob[(size_t)o0 * HW + px0 + 1]       = a01;
    ob[(size_t)(o0 + 1) * HW + px0]     = a10;
    ob[(size_t)(o0 + 1) * HW + px0 + 1] = a11;
}

extern "C" void kernel_launch(void* const* d_in, const int* in_sizes, int n_in,
                              void* d_out, int out_size, void* d_ws, size_t ws_size,
                              hipStream_t stream) {
    const float* input   = (const float*)d_in[0];
    const float* feature = (const float*)d_in[1];
    const float* w_off   = (const float*)d_in[2];
    const float* b_off   = (const float*)d_in[3];
    const float* w_mask  = (const float*)d_in[4];
    const float* b_mask  = (const float*)d_in[5];
    const float* w_dcn   = (const float*)d_in[6];
    const float* b_dcn   = (const float*)d_in[7];
    float* out = (float*)d_out;

    // ws layout (full path): no om buffer needed anymore
    unsigned short* fnhwc = (unsigned short*)d_ws;                   // 8.39 MB
    unsigned short* wBp   = fnhwc + (size_t)NB * HW * CIN;           // 258 KB
    unsigned short* wTfp  = wBp + (size_t)C_PAD * KTOT;              // 73.7 KB
    unsigned short* inb   = wTfp + 72 * 64 * 8;                      // 8.39 MB
    size_t need_full = (size_t)((char*)(inb + (size_t)NB * HW * CIN) - (char*)d_ws);
    // fallback needs om (56.6 MB) + wT (147 KB)
    size_t need_fb = ((size_t)NB * C_OM * HW + KTOT * COUT) * sizeof(float);

    if (ws_size >= need_full) {
        to_nhwc_bf16<<<NB * HW / 256, 256, 0, stream>>>(feature, fnhwc);
        to_nhwc_bf16<<<NB * HW / 256, 256, 0, stream>>>(input, inb);
        prep_wB<<<(C_PAD * KTOT + 255) / 256, 256, 0, stream>>>(w_off, w_mask, wBp);
        prep_wTf2<<<(72 * 64 * 8 + 255) / 256, 256, 0, stream>>>(w_dcn, wTfp);
        dcn_fused<<<NB * HW / 32, 256, 0, stream>>>(fnhwc, inb, wBp, wTfp,
                                                    b_off, b_mask, b_dcn, out);
    } else if (ws_size >= need_fb) {
        // fallback: pure f32 path (R1-validated)
        float* om = (float*)d_ws;
        float* wT = om + (size_t)NB * C_OM * HW;
        transpose_wdcn<<<(KTOT * COUT + 255) / 256, 256, 0, stream>>>(w_dcn, wT);
        dim3 cgrid(NB * HW / 256, 54);
        conv_om_kernel<<<cgrid, 256, 0, stream>>>(feature, w_off, b_off, w_mask, b_mask, om);
        dcn_kernel<<<NB * HW / 16, 256, 0, stream>>>(input, om, wT, b_dcn, out);
    }
}

// Round 9
// 180.699 us; speedup vs baseline: 4.5057x; 1.0649x over previous
//
#include <hip/hip_runtime.h>
#include <hip/hip_bf16.h>

#define NB 4
#define CIN 64
#define COUT 64
#define HH 128
#define WW 128
#define HW (HH*WW)
#define C_OFF 144
#define C_OM 216
#define C_PAD 224
#define KTOT 576   // CIN * 9

typedef __attribute__((ext_vector_type(8))) short bf16x8;
typedef __attribute__((ext_vector_type(4))) float f32x4;
typedef __attribute__((ext_vector_type(8))) unsigned short uv8;

__device__ inline unsigned short f2bf(float f) {
    union { float f; unsigned u; } v; v.f = f;
    unsigned r = (v.u + 0x7FFF + ((v.u >> 16) & 1)) >> 16;   // RNE
    return (unsigned short)r;
}

__device__ inline float bf2f(unsigned short h) {
    union { unsigned u; float f; } v; v.u = ((unsigned)h) << 16; return v.f;
}

// ---------------- prep kernels (all validated) ----------------

__global__ __launch_bounds__(256) void transpose_wdcn(const float* __restrict__ w,
                                                      float* __restrict__ wT) {
    int idx = blockIdx.x * 256 + threadIdx.x;
    if (idx < KTOT * COUT) {
        int o = idx & 63, kk = idx >> 6;
        wT[idx] = w[o * KTOT + kk];
    }
}

// [b][c 64][y][x] f32 -> [b][y][x][c 64] bf16
__global__ __launch_bounds__(256) void to_nhwc_bf16(const float* __restrict__ f,
                                                    unsigned short* __restrict__ o) {
    int t = blockIdx.x * 256 + threadIdx.x;      // 65536 = NB*HW
    int b = t >> 14, yx = t & 16383;
    const float* src = f + (size_t)b * CIN * HW + yx;
    unsigned short* dst = o + (size_t)t * 64;
#pragma unroll
    for (int c8 = 0; c8 < 8; ++c8) {
        uv8 v;
#pragma unroll
        for (int j = 0; j < 8; ++j) v[j] = f2bf(src[(size_t)(c8 * 8 + j) * HW]);
        *(uv8*)(dst + c8 * 8) = v;
    }
}

// wB[co][t*64+ci] bf16, co in [0,224), zeros for co>=216
__global__ __launch_bounds__(256) void prep_wB(const float* __restrict__ w_off,
                                               const float* __restrict__ w_mask,
                                               unsigned short* __restrict__ wB) {
    int idx = blockIdx.x * 256 + threadIdx.x;    // 224*576
    if (idx >= C_PAD * KTOT) return;
    int co = idx / KTOT, k = idx - co * KTOT;
    int t = k >> 6, ci = k & 63;
    float v = 0.f;
    if (co < C_OFF)      v = w_off[(size_t)co * KTOT + ci * 9 + t];
    else if (co < C_OM)  v = w_mask[(size_t)(co - C_OFF) * KTOT + ci * 9 + t];
    wB[idx] = f2bf(v);
}

// wTf2[q][co][r] bf16 = w_dcn[co][(dg*8+r)*9 + k], q = k*8+dg
__global__ __launch_bounds__(256) void prep_wTf2(const float* __restrict__ w,
                                                 unsigned short* __restrict__ wTf2) {
    int idx = blockIdx.x * 256 + threadIdx.x;    // 72*64*8 = 36864
    if (idx >= 72 * 64 * 8) return;
    int q = idx >> 9;
    int co = (idx >> 3) & 63;
    int r = idx & 7;
    int k = q >> 3, dg = q & 7;
    wTf2[idx] = f2bf(w[(size_t)co * KTOT + (dg * 8 + r) * 9 + k]);
}

// ---------------- fused: conv(offset+mask) -> LDS -> sampling -> dot ----------------
// R8-validated structure. Single change this round: om_l aliases the val_q
// arena (they never coexist: conv writes om_l at +4KB while Ash uses [0,4K);
// sampling reads its 27 om values into registers, then a barrier, THEN
// overwrites the arena with val_q). LDS 66.5 KB -> 36.9 KB => 4 blocks/CU.

__global__ __launch_bounds__(256, 4) void dcn_fused(
    const unsigned short* __restrict__ fnhwc,  // feature NHWC bf16
    const unsigned short* __restrict__ inb,    // input NHWC bf16
    const unsigned short* __restrict__ wB,     // [224][576] bf16
    const unsigned short* __restrict__ wTf2,   // [72][64][8] bf16
    const float* __restrict__ b_off, const float* __restrict__ b_mask,
    const float* __restrict__ b_dcn,
    float* __restrict__ out)
{
    __shared__ __align__(16) unsigned char smem[72 * 32 * 8 * 2];   // 36864 B arena
    unsigned short* val_q = (unsigned short*)smem;                  // [72][32][8] bf16
    unsigned short* Ash   = (unsigned short*)smem;                  // conv staging (4 KB)
    float* om_l           = (float*)(smem + 4096);                  // [224][33] f32 (29.6 KB)

    int tid = threadIdx.x;
    int bid = blockIdx.x;                 // 2048
    int b   = bid >> 9;
    int hw0 = (bid & 511) << 5;           // 32-px tile, row-aligned
    int ho  = hw0 >> 7;
    int wo0 = hw0 & 127;

    int lane = tid & 63, wave = tid >> 6;
    int arow = lane & 15, g = lane >> 4;
    int h  = wave & 1;                    // px 16-half
    int ws = wave >> 1;                   // co 112-half

    // ---- conv phase ----
    f32x4 acc[7];
#pragma unroll
    for (int n = 0; n < 7; ++n) acc[n] = (f32x4){0.f, 0.f, 0.f, 0.f};

    int px_w = tid >> 3;                  // 0..31
    int c8_w = tid & 7;

    for (int t = 0; t < 9; ++t) {
        int ky = t / 3, kx = t - ky * 3;
        int y = ho + ky - 1;
        bool yv = (unsigned)y < (unsigned)HH;
        __syncthreads();
        {
            int x = wo0 + px_w + kx - 1;
            uv8 v = (uv8){0, 0, 0, 0, 0, 0, 0, 0};
            if (yv && (unsigned)x < (unsigned)WW)
                v = *(const uv8*)(fnhwc + ((size_t)((b * HH + y) * WW + x) << 6) + c8_w * 8);
            int off16 = (c8_w << 4) ^ ((px_w & 7) << 4);
            *(uv8*)((char*)Ash + px_w * 128 + off16) = v;
        }
        __syncthreads();
#pragma unroll
        for (int half = 0; half < 2; ++half) {
            int px = h * 16 + arow;
            int kb = half * 64 + g * 16;
            bf16x8 a = *(const bf16x8*)((const char*)Ash + px * 128 + (kb ^ ((px & 7) << 4)));
            int kglob = t * 64 + half * 32 + g * 8;
#pragma unroll
            for (int n = 0; n < 7; ++n) {
                int co = ws * 112 + n * 16 + arow;
                bf16x8 bf = *(const bf16x8*)(wB + (size_t)co * KTOT + kglob);
                acc[n] = __builtin_amdgcn_mfma_f32_16x16x32_bf16(a, bf, acc[n], 0, 0, 0);
            }
        }
    }

    // conv epilogue -> om_l (bias + sigmoid for mask channels); om_l disjoint from Ash
#pragma unroll
    for (int n = 0; n < 7; ++n) {
        int co = ws * 112 + n * 16 + arow;
        if (co < C_OM) {
            float bias = (co < C_OFF) ? b_off[co] : b_mask[co - C_OFF];
#pragma unroll
            for (int j = 0; j < 4; ++j) {
                float v = acc[n][j] + bias;
                if (co >= C_OFF) v = 1.f / (1.f + __expf(-v));
                om_l[co * 33 + h * 16 + g * 4 + j] = v;
            }
        }
    }
    __syncthreads();

    // ---- om -> registers (before val_q overwrites the arena) ----
    int px = tid & 31;
    int dg = tid >> 5;                    // 0..7

    float dy[9], dxv[9], mk[9];
#pragma unroll
    for (int k = 0; k < 9; ++k) {
        dy[k]  = om_l[(dg * 18 + 2 * k) * 33 + px];
        dxv[k] = om_l[(dg * 18 + 2 * k + 1) * 33 + px];
        mk[k]  = om_l[(C_OFF + dg * 9 + k) * 33 + px];
    }
    __syncthreads();                      // om_l reads complete; arena may be reused

    // ---- sampling phase (verbatim R7/R8) ----
    const unsigned short* plane0 = inb + ((size_t)b * HW << 6) + dg * 8;
    float yb = (float)(ho - 1);
    float xb = (float)(wo0 + px - 1);

#pragma unroll
    for (int k = 0; k < 9; ++k) {
        float ys = dy[k] + yb + (float)(k / 3);
        float xs = dxv[k] + xb + (float)(k % 3);
        float y0f = floorf(ys), x0f = floorf(xs);
        float fy = ys - y0f, fx = xs - x0f;
        int y0 = (int)y0f, x0 = (int)x0f;
        bool yv0 = (unsigned)y0 < (unsigned)HH;
        bool yv1 = (unsigned)(y0 + 1) < (unsigned)HH;
        bool xv0 = (unsigned)x0 < (unsigned)WW;
        bool xv1 = (unsigned)(x0 + 1) < (unsigned)WW;
        const unsigned short* pp = plane0 + (y0 * WW + x0) * 64;
        uv8 c00 = (uv8){0,0,0,0,0,0,0,0};
        uv8 c01 = c00, c10 = c00, c11 = c00;
        if (yv0 && xv0) c00 = *(const uv8*)(pp);
        if (yv0 && xv1) c01 = *(const uv8*)(pp + 64);
        if (yv1 && xv0) c10 = *(const uv8*)(pp + 64 * WW);
        if (yv1 && xv1) c11 = *(const uv8*)(pp + 64 * WW + 64);
        uv8 r;
#pragma unroll
        for (int j = 0; j < 8; ++j) {
            float v00 = bf2f(c00[j]), v01 = bf2f(c01[j]);
            float v10 = bf2f(c10[j]), v11 = bf2f(c11[j]);
            float top = v00 + (v01 - v00) * fx;
            float bot = v10 + (v11 - v10) * fx;
            float v = top + (bot - top) * fy;
            r[j] = f2bf(v * mk[k]);
        }
        *(uv8*)(val_q + (k * 8 + dg) * 256 + px * 8) = r;
    }
    __syncthreads();

    // ---- dot phase (verbatim R7/R8) ----
    int nh = wave >> 1;

    f32x4 dacc[2];
    dacc[0] = dacc[1] = (f32x4){0.f, 0.f, 0.f, 0.f};
#pragma unroll
    for (int s = 0; s < 18; ++s) {
        int q = s * 4 + g;
        bf16x8 a = *(const bf16x8*)(val_q + q * 256 + (h * 16 + arow) * 8);
#pragma unroll
        for (int n = 0; n < 2; ++n) {
            int co = nh * 32 + n * 16 + arow;
            bf16x8 bf = *(const bf16x8*)(wTf2 + ((size_t)q * 64 + co) * 8);
            dacc[n] = __builtin_amdgcn_mfma_f32_16x16x32_bf16(a, bf, dacc[n], 0, 0, 0);
        }
    }

#pragma unroll
    for (int n = 0; n < 2; ++n) {
        int co = nh * 32 + n * 16 + arow;
        float bias = b_dcn[co];
        f32x4 r;
#pragma unroll
        for (int j = 0; j < 4; ++j) r[j] = dacc[n][j] + bias;
        *(f32x4*)(out + (size_t)b * COUT * HW + (size_t)co * HW + hw0 + h * 16 + g * 4) = r;
    }
}

// ---------------- fallback f32 kernels (if ws too small) ----------------

__global__ __launch_bounds__(256) void conv_om_kernel(
    const float* __restrict__ feature,
    const float* __restrict__ w_off, const float* __restrict__ b_off,
    const float* __restrict__ w_mask, const float* __restrict__ b_mask,
    float* __restrict__ om)
{
    int tid = threadIdx.x;
    int p = blockIdx.x * 256 + tid;
    int cg = blockIdx.y;
    int b  = p >> 14;
    int hw = p & (HW - 1);
    int ho = hw >> 7;
    int wo = hw & 127;
    int co0 = cg * 4;

    float acc[4];
    const float* wb[4];
#pragma unroll
    for (int j = 0; j < 4; ++j) {
        int co = co0 + j;
        if (co < C_OFF) { acc[j] = b_off[co];          wb[j] = w_off  + (size_t)co * 576; }
        else            { acc[j] = b_mask[co - C_OFF]; wb[j] = w_mask + (size_t)(co - C_OFF) * 576; }
    }
    const float* fb = feature + (size_t)b * CIN * HW;
    for (int ci = 0; ci < CIN; ++ci) {
        const float* fp = fb + ci * HW;
#pragma unroll
        for (int ky = 0; ky < 3; ++ky) {
            int y = ho + ky - 1;
            bool yvb = (unsigned)y < (unsigned)HH;
#pragma unroll
            for (int kx = 0; kx < 3; ++kx) {
                int x = wo + kx - 1;
                float v = (yvb && (unsigned)x < (unsigned)WW) ? fp[y * WW + x] : 0.f;
                int wi = ci * 9 + ky * 3 + kx;
#pragma unroll
                for (int j = 0; j < 4; ++j) acc[j] += v * wb[j][wi];
            }
        }
    }
    size_t obase = (size_t)b * C_OM * HW + hw;
#pragma unroll
    for (int j = 0; j < 4; ++j) {
        int co = co0 + j;
        float v = acc[j];
        if (co >= C_OFF) v = 1.f / (1.f + __expf(-v));
        om[obase + (size_t)co * HW] = v;
    }
}

__global__ __launch_bounds__(256) void dcn_kernel(
    const float* __restrict__ input,
    const float* __restrict__ om,
    const float* __restrict__ wT,
    const float* __restrict__ b_dcn,
    float* __restrict__ out)
{
    __shared__ float om_l[C_OM * 16];
    __shared__ float val_l[KTOT * 16];

    int tid  = threadIdx.x;
    int tile = blockIdx.x;
    int b    = tile >> 10;
    int hw0  = (tile & 1023) << 4;
    int ho   = hw0 >> 7;
    int wo0  = hw0 & 127;

    const float* omg = om + (size_t)b * C_OM * HW + hw0;
    for (int i = tid; i < C_OM * 16; i += 256) {
        int ch = i >> 4, px = i & 15;
        om_l[i] = omg[(size_t)ch * HW + px];
    }
    __syncthreads();

    for (int pair = tid; pair < 1024; pair += 256) {
        int px = pair & 15, c = pair >> 4;
        int dg = c >> 3;
        const float* plane = input + (size_t)(b * CIN + c) * HW;
        float yb = (float)(ho - 1);
        float xb = (float)(wo0 + px - 1);
#pragma unroll
        for (int k = 0; k < 9; ++k) {
            float dyv = om_l[(dg * 18 + 2 * k) * 16 + px];
            float dxv = om_l[(dg * 18 + 2 * k + 1) * 16 + px];
            float m  = om_l[(C_OFF + dg * 9 + k) * 16 + px];
            float ys = dyv + yb + (float)(k / 3);
            float xs = dxv + xb + (float)(k % 3);
            float y0f = floorf(ys), x0f = floorf(xs);
            float wy = ys - y0f, wx = xs - x0f;
            int y0 = (int)y0f, x0 = (int)x0f;
            bool yv0 = (unsigned)y0 < (unsigned)HH;
            bool yv1 = (unsigned)(y0 + 1) < (unsigned)HH;
            bool xv0 = (unsigned)x0 < (unsigned)WW;
            bool xv1 = (unsigned)(x0 + 1) < (unsigned)WW;
            const float* r0 = plane + y0 * WW + x0;
            float v00 = (yv0 && xv0) ? r0[0]      : 0.f;
            float v01 = (yv0 && xv1) ? r0[1]      : 0.f;
            float v10 = (yv1 && xv0) ? r0[WW]     : 0.f;
            float v11 = (yv1 && xv1) ? r0[WW + 1] : 0.f;
            float top = v00 + (v01 - v00) * wx;
            float bot = v10 + (v11 - v10) * wx;
            float v = top + (bot - top) * wy;
            val_l[(c * 9 + k) * 16 + px] = v * m;
        }
    }
    __syncthreads();

    int o2 = tid & 31;
    int ph = tid >> 5;
    int o0 = o2 * 2, px0 = ph * 2;
    float a00 = b_dcn[o0],     a01 = b_dcn[o0];
    float a10 = b_dcn[o0 + 1], a11 = b_dcn[o0 + 1];
    for (int kk = 0; kk < KTOT; ++kk) {
        float2 wv = *reinterpret_cast<const float2*>(wT + kk * 64 + o0);
        float va = val_l[kk * 16 + px0];
        float vb = val_l[kk * 16 + px0 + 1];
        a00 += wv.x * va; a01 += wv.x * vb;
        a10 += wv.y * va; a11 += wv.y * vb;
    }
    float* ob = out + (size_t)b * COUT * HW + hw0;
    ob[(size_t)o0 * HW + px0]           = a00;
    ob[(size_t)o0 * HW + px0 + 1]       = a01;
    ob[(size_t)(o0 + 1) * HW + px0]     = a10;
    ob[(size_t)(o0 + 1) * HW + px0 + 1] = a11;
}

extern "C" void kernel_launch(void* const* d_in, const int* in_sizes, int n_in,
                              void* d_out, int out_size, void* d_ws, size_t ws_size,
                              hipStream_t stream) {
    const float* input   = (const float*)d_in[0];
    const float* feature = (const float*)d_in[1];
    const float* w_off   = (const float*)d_in[2];
    const float* b_off   = (const float*)d_in[3];
    const float* w_mask  = (const float*)d_in[4];
    const float* b_mask  = (const float*)d_in[5];
    const float* w_dcn   = (const float*)d_in[6];
    const float* b_dcn   = (const float*)d_in[7];
    float* out = (float*)d_out;

    // ws layout (full path): no om buffer needed
    unsigned short* fnhwc = (unsigned short*)d_ws;                   // 8.39 MB
    unsigned short* wBp   = fnhwc + (size_t)NB * HW * CIN;           // 258 KB
    unsigned short* wTfp  = wBp + (size_t)C_PAD * KTOT;              // 73.7 KB
    unsigned short* inb   = wTfp + 72 * 64 * 8;                      // 8.39 MB
    size_t need_full = (size_t)((char*)(inb + (size_t)NB * HW * CIN) - (char*)d_ws);
    // fallback needs om (56.6 MB) + wT (147 KB)
    size_t need_fb = ((size_t)NB * C_OM * HW + KTOT * COUT) * sizeof(float);

    if (ws_size >= need_full) {
        to_nhwc_bf16<<<NB * HW / 256, 256, 0, stream>>>(feature, fnhwc);
        to_nhwc_bf16<<<NB * HW / 256, 256, 0, stream>>>(input, inb);
        prep_wB<<<(C_PAD * KTOT + 255) / 256, 256, 0, stream>>>(w_off, w_mask, wBp);
        prep_wTf2<<<(72 * 64 * 8 + 255) / 256, 256, 0, stream>>>(w_dcn, wTfp);
        dcn_fused<<<NB * HW / 32, 256, 0, stream>>>(fnhwc, inb, wBp, wTfp,
                                                    b_off, b_mask, b_dcn, out);
    } else if (ws_size >= need_fb) {
        // fallback: pure f32 path (R1-validated)
        float* om = (float*)d_ws;
        float* wT = om + (size_t)NB * C_OM * HW;
        transpose_wdcn<<<(KTOT * COUT + 255) / 256, 256, 0, stream>>>(w_dcn, wT);
        dim3 cgrid(NB * HW / 256, 54);
        conv_om_kernel<<<cgrid, 256, 0, stream>>>(feature, w_off, b_off, w_mask, b_mask, om);
        dcn_kernel<<<NB * HW / 16, 256, 0, stream>>>(input, om, wT, b_dcn, out);
    }
}

// Round 10
// 94.770 us; speedup vs baseline: 8.5911x; 1.9067x over previous
//
#include <hip/hip_runtime.h>
#include <hip/hip_bf16.h>

#define NB 4
#define CIN 64
#define COUT 64
#define HH 128
#define WW 128
#define HW (HH*WW)
#define C_OFF 144
#define C_OM 216
#define C_PAD 224
#define KTOT 576   // CIN * 9

typedef __attribute__((ext_vector_type(8))) short bf16x8;
typedef __attribute__((ext_vector_type(4))) float f32x4;
typedef __attribute__((ext_vector_type(8))) unsigned short uv8;

__device__ inline unsigned short f2bf(float f) {
    union { float f; unsigned u; } v; v.f = f;
    unsigned r = (v.u + 0x7FFF + ((v.u >> 16) & 1)) >> 16;   // RNE
    return (unsigned short)r;
}

__device__ inline float bf2f(unsigned short h) {
    union { unsigned u; float f; } v; v.u = ((unsigned)h) << 16; return v.f;
}

// ---------------- prep kernels (all validated) ----------------

__global__ __launch_bounds__(256) void transpose_wdcn(const float* __restrict__ w,
                                                      float* __restrict__ wT) {
    int idx = blockIdx.x * 256 + threadIdx.x;
    if (idx < KTOT * COUT) {
        int o = idx & 63, kk = idx >> 6;
        wT[idx] = w[o * KTOT + kk];
    }
}

// [b][c 64][y][x] f32 -> [b][y][x][c 64] bf16
__global__ __launch_bounds__(256) void to_nhwc_bf16(const float* __restrict__ f,
                                                    unsigned short* __restrict__ o) {
    int t = blockIdx.x * 256 + threadIdx.x;      // 65536 = NB*HW
    int b = t >> 14, yx = t & 16383;
    const float* src = f + (size_t)b * CIN * HW + yx;
    unsigned short* dst = o + (size_t)t * 64;
#pragma unroll
    for (int c8 = 0; c8 < 8; ++c8) {
        uv8 v;
#pragma unroll
        for (int j = 0; j < 8; ++j) v[j] = f2bf(src[(size_t)(c8 * 8 + j) * HW]);
        *(uv8*)(dst + c8 * 8) = v;
    }
}

// wB[co][t*64+ci] bf16, co in [0,224), zeros for co>=216
__global__ __launch_bounds__(256) void prep_wB(const float* __restrict__ w_off,
                                               const float* __restrict__ w_mask,
                                               unsigned short* __restrict__ wB) {
    int idx = blockIdx.x * 256 + threadIdx.x;    // 224*576
    if (idx >= C_PAD * KTOT) return;
    int co = idx / KTOT, k = idx - co * KTOT;
    int t = k >> 6, ci = k & 63;
    float v = 0.f;
    if (co < C_OFF)      v = w_off[(size_t)co * KTOT + ci * 9 + t];
    else if (co < C_OM)  v = w_mask[(size_t)(co - C_OFF) * KTOT + ci * 9 + t];
    wB[idx] = f2bf(v);
}

// wTf2[q][co][r] bf16 = w_dcn[co][(dg*8+r)*9 + k], q = k*8+dg
__global__ __launch_bounds__(256) void prep_wTf2(const float* __restrict__ w,
                                                 unsigned short* __restrict__ wTf2) {
    int idx = blockIdx.x * 256 + threadIdx.x;    // 72*64*8 = 36864
    if (idx >= 72 * 64 * 8) return;
    int q = idx >> 9;
    int co = (idx >> 3) & 63;
    int r = idx & 7;
    int k = q >> 3, dg = q & 7;
    wTf2[idx] = f2bf(w[(size_t)co * KTOT + (dg * 8 + r) * 9 + k]);
}

// ---------------- fused: conv(offset+mask) -> LDS -> sampling -> dot ----------------
// R9-validated structure. Single change this round: the per-tap wB slice
// (224x64 bf16 = 28.7KB) is staged into LDS (Bsh, XOR-swizzled like Ash) and
// the conv MFMA B-fragments become ds_reads. Kills the h-wave duplication and
// the 200cy-latency scattered L2 fragment loads. LDS arena still 36.9KB:
// conv uses Ash[0,4K)+Bsh[4K,32.7K); after a new post-loop barrier, om_l
// overwrites [0,29.6K); then val_q reuses [0,36.9K) (R9 discipline).

__global__ __launch_bounds__(256, 4) void dcn_fused(
    const unsigned short* __restrict__ fnhwc,  // feature NHWC bf16
    const unsigned short* __restrict__ inb,    // input NHWC bf16
    const unsigned short* __restrict__ wB,     // [224][576] bf16
    const unsigned short* __restrict__ wTf2,   // [72][64][8] bf16
    const float* __restrict__ b_off, const float* __restrict__ b_mask,
    const float* __restrict__ b_dcn,
    float* __restrict__ out)
{
    __shared__ __align__(16) unsigned char smem[72 * 32 * 8 * 2];   // 36864 B arena
    unsigned short* val_q = (unsigned short*)smem;                  // [72][32][8] bf16
    unsigned short* Ash   = (unsigned short*)smem;                  // conv A staging [0,4096)
    unsigned short* Bsh   = (unsigned short*)(smem + 4096);         // conv B tile [4096,32768)
    float* om_l           = (float*)smem;                           // [224][33] f32 [0,29568)

    int tid = threadIdx.x;
    int bid = blockIdx.x;                 // 2048
    int b   = bid >> 9;
    int hw0 = (bid & 511) << 5;           // 32-px tile, row-aligned
    int ho  = hw0 >> 7;
    int wo0 = hw0 & 127;

    int lane = tid & 63, wave = tid >> 6;
    int arow = lane & 15, g = lane >> 4;
    int h  = wave & 1;                    // px 16-half
    int ws = wave >> 1;                   // co 112-half

    // ---- conv phase ----
    f32x4 acc[7];
#pragma unroll
    for (int n = 0; n < 7; ++n) acc[n] = (f32x4){0.f, 0.f, 0.f, 0.f};

    int px_w = tid >> 3;                  // 0..31
    int c8_w = tid & 7;

    for (int t = 0; t < 9; ++t) {
        int ky = t / 3, kx = t - ky * 3;
        int y = ho + ky - 1;
        bool yv = (unsigned)y < (unsigned)HH;
        __syncthreads();
        // stage A (32px x 64ci, swizzled) — unchanged
        {
            int x = wo0 + px_w + kx - 1;
            uv8 v = (uv8){0, 0, 0, 0, 0, 0, 0, 0};
            if (yv && (unsigned)x < (unsigned)WW)
                v = *(const uv8*)(fnhwc + ((size_t)((b * HH + y) * WW + x) << 6) + c8_w * 8);
            int off16 = (c8_w << 4) ^ ((px_w & 7) << 4);
            *(uv8*)((char*)Ash + px_w * 128 + off16) = v;
        }
        // stage B tile for this tap: 224 co x 64 ci bf16, swizzled rows
#pragma unroll
        for (int r = 0; r < 7; ++r) {
            int idx = r * 256 + tid;      // 0..1791 = 224*8 chunks
            int co = idx >> 3, c8 = idx & 7;
            uv8 v = *(const uv8*)(wB + (size_t)co * KTOT + t * 64 + c8 * 8);
            *(uv8*)((char*)Bsh + co * 128 + ((c8 << 4) ^ ((co & 7) << 4))) = v;
        }
        __syncthreads();
#pragma unroll
        for (int half = 0; half < 2; ++half) {
            int px = h * 16 + arow;
            int kb = half * 64 + g * 16;
            bf16x8 a = *(const bf16x8*)((const char*)Ash + px * 128 + (kb ^ ((px & 7) << 4)));
#pragma unroll
            for (int n = 0; n < 7; ++n) {
                int co = ws * 112 + n * 16 + arow;   // co&7 == arow&7 (112,16 ≡ 0 mod 8)
                bf16x8 bf = *(const bf16x8*)((const char*)Bsh + co * 128 +
                                             (kb ^ ((co & 7) << 4)));
                acc[n] = __builtin_amdgcn_mfma_f32_16x16x32_bf16(a, bf, acc[n], 0, 0, 0);
            }
        }
    }
    __syncthreads();   // NEW: all Ash/Bsh reads done before om_l overwrites [0,29.6K)

    // conv epilogue -> om_l (bias + sigmoid for mask channels)
#pragma unroll
    for (int n = 0; n < 7; ++n) {
        int co = ws * 112 + n * 16 + arow;
        if (co < C_OM) {
            float bias = (co < C_OFF) ? b_off[co] : b_mask[co - C_OFF];
#pragma unroll
            for (int j = 0; j < 4; ++j) {
                float v = acc[n][j] + bias;
                if (co >= C_OFF) v = 1.f / (1.f + __expf(-v));
                om_l[co * 33 + h * 16 + g * 4 + j] = v;
            }
        }
    }
    __syncthreads();

    // ---- om -> registers (before val_q overwrites the arena) ----
    int px = tid & 31;
    int dg = tid >> 5;                    // 0..7

    float dy[9], dxv[9], mk[9];
#pragma unroll
    for (int k = 0; k < 9; ++k) {
        dy[k]  = om_l[(dg * 18 + 2 * k) * 33 + px];
        dxv[k] = om_l[(dg * 18 + 2 * k + 1) * 33 + px];
        mk[k]  = om_l[(C_OFF + dg * 9 + k) * 33 + px];
    }
    __syncthreads();                      // om_l reads complete; arena may be reused

    // ---- sampling phase (verbatim R7/R8/R9) ----
    const unsigned short* plane0 = inb + ((size_t)b * HW << 6) + dg * 8;
    float yb = (float)(ho - 1);
    float xb = (float)(wo0 + px - 1);

#pragma unroll
    for (int k = 0; k < 9; ++k) {
        float ys = dy[k] + yb + (float)(k / 3);
        float xs = dxv[k] + xb + (float)(k % 3);
        float y0f = floorf(ys), x0f = floorf(xs);
        float fy = ys - y0f, fx = xs - x0f;
        int y0 = (int)y0f, x0 = (int)x0f;
        bool yv0 = (unsigned)y0 < (unsigned)HH;
        bool yv1 = (unsigned)(y0 + 1) < (unsigned)HH;
        bool xv0 = (unsigned)x0 < (unsigned)WW;
        bool xv1 = (unsigned)(x0 + 1) < (unsigned)WW;
        const unsigned short* pp = plane0 + (y0 * WW + x0) * 64;
        uv8 c00 = (uv8){0,0,0,0,0,0,0,0};
        uv8 c01 = c00, c10 = c00, c11 = c00;
        if (yv0 && xv0) c00 = *(const uv8*)(pp);
        if (yv0 && xv1) c01 = *(const uv8*)(pp + 64);
        if (yv1 && xv0) c10 = *(const uv8*)(pp + 64 * WW);
        if (yv1 && xv1) c11 = *(const uv8*)(pp + 64 * WW + 64);
        uv8 r;
#pragma unroll
        for (int j = 0; j < 8; ++j) {
            float v00 = bf2f(c00[j]), v01 = bf2f(c01[j]);
            float v10 = bf2f(c10[j]), v11 = bf2f(c11[j]);
            float top = v00 + (v01 - v00) * fx;
            float bot = v10 + (v11 - v10) * fx;
            float v = top + (bot - top) * fy;
            r[j] = f2bf(v * mk[k]);
        }
        *(uv8*)(val_q + (k * 8 + dg) * 256 + px * 8) = r;
    }
    __syncthreads();

    // ---- dot phase (verbatim R7/R8/R9) ----
    int nh = wave >> 1;

    f32x4 dacc[2];
    dacc[0] = dacc[1] = (f32x4){0.f, 0.f, 0.f, 0.f};
#pragma unroll
    for (int s = 0; s < 18; ++s) {
        int q = s * 4 + g;
        bf16x8 a = *(const bf16x8*)(val_q + q * 256 + (h * 16 + arow) * 8);
#pragma unroll
        for (int n = 0; n < 2; ++n) {
            int co = nh * 32 + n * 16 + arow;
            bf16x8 bf = *(const bf16x8*)(wTf2 + ((size_t)q * 64 + co) * 8);
            dacc[n] = __builtin_amdgcn_mfma_f32_16x16x32_bf16(a, bf, dacc[n], 0, 0, 0);
        }
    }

#pragma unroll
    for (int n = 0; n < 2; ++n) {
        int co = nh * 32 + n * 16 + arow;
        float bias = b_dcn[co];
        f32x4 r;
#pragma unroll
        for (int j = 0; j < 4; ++j) r[j] = dacc[n][j] + bias;
        *(f32x4*)(out + (size_t)b * COUT * HW + (size_t)co * HW + hw0 + h * 16 + g * 4) = r;
    }
}

// ---------------- fallback f32 kernels (if ws too small) ----------------

__global__ __launch_bounds__(256) void conv_om_kernel(
    const float* __restrict__ feature,
    const float* __restrict__ w_off, const float* __restrict__ b_off,
    const float* __restrict__ w_mask, const float* __restrict__ b_mask,
    float* __restrict__ om)
{
    int tid = threadIdx.x;
    int p = blockIdx.x * 256 + tid;
    int cg = blockIdx.y;
    int b  = p >> 14;
    int hw = p & (HW - 1);
    int ho = hw >> 7;
    int wo = hw & 127;
    int co0 = cg * 4;

    float acc[4];
    const float* wb[4];
#pragma unroll
    for (int j = 0; j < 4; ++j) {
        int co = co0 + j;
        if (co < C_OFF) { acc[j] = b_off[co];          wb[j] = w_off  + (size_t)co * 576; }
        else            { acc[j] = b_mask[co - C_OFF]; wb[j] = w_mask + (size_t)(co - C_OFF) * 576; }
    }
    const float* fb = feature + (size_t)b * CIN * HW;
    for (int ci = 0; ci < CIN; ++ci) {
        const float* fp = fb + ci * HW;
#pragma unroll
        for (int ky = 0; ky < 3; ++ky) {
            int y = ho + ky - 1;
            bool yvb = (unsigned)y < (unsigned)HH;
#pragma unroll
            for (int kx = 0; kx < 3; ++kx) {
                int x = wo + kx - 1;
                float v = (yvb && (unsigned)x < (unsigned)WW) ? fp[y * WW + x] : 0.f;
                int wi = ci * 9 + ky * 3 + kx;
#pragma unroll
                for (int j = 0; j < 4; ++j) acc[j] += v * wb[j][wi];
            }
        }
    }
    size_t obase = (size_t)b * C_OM * HW + hw;
#pragma unroll
    for (int j = 0; j < 4; ++j) {
        int co = co0 + j;
        float v = acc[j];
        if (co >= C_OFF) v = 1.f / (1.f + __expf(-v));
        om[obase + (size_t)co * HW] = v;
    }
}

__global__ __launch_bounds__(256) void dcn_kernel(
    const float* __restrict__ input,
    const float* __restrict__ om,
    const float* __restrict__ wT,
    const float* __restrict__ b_dcn,
    float* __restrict__ out)
{
    __shared__ float om_l[C_OM * 16];
    __shared__ float val_l[KTOT * 16];

    int tid  = threadIdx.x;
    int tile = blockIdx.x;
    int b    = tile >> 10;
    int hw0  = (tile & 1023) << 4;
    int ho   = hw0 >> 7;
    int wo0  = hw0 & 127;

    const float* omg = om + (size_t)b * C_OM * HW + hw0;
    for (int i = tid; i < C_OM * 16; i += 256) {
        int ch = i >> 4, px = i & 15;
        om_l[i] = omg[(size_t)ch * HW + px];
    }
    __syncthreads();

    for (int pair = tid; pair < 1024; pair += 256) {
        int px = pair & 15, c = pair >> 4;
        int dg = c >> 3;
        const float* plane = input + (size_t)(b * CIN + c) * HW;
        float yb = (float)(ho - 1);
        float xb = (float)(wo0 + px - 1);
#pragma unroll
        for (int k = 0; k < 9; ++k) {
            float dyv = om_l[(dg * 18 + 2 * k) * 16 + px];
            float dxv = om_l[(dg * 18 + 2 * k + 1) * 16 + px];
            float m  = om_l[(C_OFF + dg * 9 + k) * 16 + px];
            float ys = dyv + yb + (float)(k / 3);
            float xs = dxv + xb + (float)(k % 3);
            float y0f = floorf(ys), x0f = floorf(xs);
            float wy = ys - y0f, wx = xs - x0f;
            int y0 = (int)y0f, x0 = (int)x0f;
            bool yv0 = (unsigned)y0 < (unsigned)HH;
            bool yv1 = (unsigned)(y0 + 1) < (unsigned)HH;
            bool xv0 = (unsigned)x0 < (unsigned)WW;
            bool xv1 = (unsigned)(x0 + 1) < (unsigned)WW;
            const float* r0 = plane + y0 * WW + x0;
            float v00 = (yv0 && xv0) ? r0[0]      : 0.f;
            float v01 = (yv0 && xv1) ? r0[1]      : 0.f;
            float v10 = (yv1 && xv0) ? r0[WW]     : 0.f;
            float v11 = (yv1 && xv1) ? r0[WW + 1] : 0.f;
            float top = v00 + (v01 - v00) * wx;
            float bot = v10 + (v11 - v10) * wx;
            float v = top + (bot - top) * wy;
            val_l[(c * 9 + k) * 16 + px] = v * m;
        }
    }
    __syncthreads();

    int o2 = tid & 31;
    int ph = tid >> 5;
    int o0 = o2 * 2, px0 = ph * 2;
    float a00 = b_dcn[o0],     a01 = b_dcn[o0];
    float a10 = b_dcn[o0 + 1], a11 = b_dcn[o0 + 1];
    for (int kk = 0; kk < KTOT; ++kk) {
        float2 wv = *reinterpret_cast<const float2*>(wT + kk * 64 + o0);
        float va = val_l[kk * 16 + px0];
        float vb = val_l[kk * 16 + px0 + 1];
        a00 += wv.x * va; a01 += wv.x * vb;
        a10 += wv.y * va; a11 += wv.y * vb;
    }
    float* ob = out + (size_t)b * COUT * HW + hw0;
    ob[(size_t)o0 * HW + px0]           = a00;
    ob[(size_t)o0 * HW + px0 + 1]       = a01;
    ob[(size_t)(o0 + 1) * HW + px0]     = a10;
    ob[(size_t)(o0 + 1) * HW + px0 + 1] = a11;
}

extern "C" void kernel_launch(void* const* d_in, const int* in_sizes, int n_in,
                              void* d_out, int out_size, void* d_ws, size_t ws_size,
                              hipStream_t stream) {
    const float* input   = (const float*)d_in[0];
    const float* feature = (const float*)d_in[1];
    const float* w_off   = (const float*)d_in[2];
    const float* b_off   = (const float*)d_in[3];
    const float* w_mask  = (const float*)d_in[4];
    const float* b_mask  = (const float*)d_in[5];
    const float* w_dcn   = (const float*)d_in[6];
    const float* b_dcn   = (const float*)d_in[7];
    float* out = (float*)d_out;

    // ws layout (full path): no om buffer needed
    unsigned short* fnhwc = (unsigned short*)d_ws;                   // 8.39 MB
    unsigned short* wBp   = fnhwc + (size_t)NB * HW * CIN;           // 258 KB
    unsigned short* wTfp  = wBp + (size_t)C_PAD * KTOT;              // 73.7 KB
    unsigned short* inb   = wTfp + 72 * 64 * 8;                      // 8.39 MB
    size_t need_full = (size_t)((char*)(inb + (size_t)NB * HW * CIN) - (char*)d_ws);
    // fallback needs om (56.6 MB) + wT (147 KB)
    size_t need_fb = ((size_t)NB * C_OM * HW + KTOT * COUT) * sizeof(float);

    if (ws_size >= need_full) {
        to_nhwc_bf16<<<NB * HW / 256, 256, 0, stream>>>(feature, fnhwc);
        to_nhwc_bf16<<<NB * HW / 256, 256, 0, stream>>>(input, inb);
        prep_wB<<<(C_PAD * KTOT + 255) / 256, 256, 0, stream>>>(w_off, w_mask, wBp);
        prep_wTf2<<<(72 * 64 * 8 + 255) / 256, 256, 0, stream>>>(w_dcn, wTfp);
        dcn_fused<<<NB * HW / 32, 256, 0, stream>>>(fnhwc, inb, wBp, wTfp,
                                                    b_off, b_mask, b_dcn, out);
    } else if (ws_size >= need_fb) {
        // fallback: pure f32 path (R1-validated)
        float* om = (float*)d_ws;
        float* wT = om + (size_t)NB * C_OM * HW;
        transpose_wdcn<<<(KTOT * COUT + 255) / 256, 256, 0, stream>>>(w_dcn, wT);
        dim3 cgrid(NB * HW / 256, 54);
        conv_om_kernel<<<cgrid, 256, 0, stream>>>(feature, w_off, b_off, w_mask, b_mask, om);
        dcn_kernel<<<NB * HW / 16, 256, 0, stream>>>(input, om, wT, b_dcn, out);
    }
}